// Round 12
// baseline (444.734 us; speedup 1.0000x reference)
//
#include <hip/hip_runtime.h>
#include <hip/hip_bf16.h>

#define N_NODES 50000
#define N_EDGES 600000

typedef short bf16x8 __attribute__((ext_vector_type(8)));
typedef float f32x4 __attribute__((ext_vector_type(4)));

__device__ __forceinline__ float leaky(float e) { return e > 0.f ? e : 0.2f * e; }
__device__ __forceinline__ unsigned short f2b(float f) {
  __hip_bfloat16 h = __float2bfloat16(f);
  return *reinterpret_cast<unsigned short*>(&h);
}
__device__ __forceinline__ float blo(unsigned int u) { return __uint_as_float(u << 16); }
__device__ __forceinline__ float bhi(unsigned int u) { return __uint_as_float(u & 0xffff0000u); }
__device__ __forceinline__ float pick4(float a0, float a1, float a2, float a3, int r) {
  float x = (r & 1) ? a1 : a0;
  float y = (r & 1) ? a3 : a2;
  return (r & 2) ? y : x;
}

// ------------- edge convert (detect int64 vs int32) + degree count -------------
__global__ void k_convert(const int* __restrict__ e, int* __restrict__ src32,
                          int* __restrict__ dst32, int* __restrict__ deg) {
  __shared__ int sflag;
  int tid = threadIdx.x;
  if (tid < 64) {  // wave 0: sample odd int32 words; all-zero => int64 input
    int idx = 1 + 2 * tid * 4096;
    int v = e[idx];
    unsigned long long nz = __ballot(v != 0);
    if (tid == 0) sflag = (nz == 0ULL) ? 1 : 0;
  }
  __syncthreads();
  int f = sflag;
  int i = blockIdx.x * 256 + tid;
  if (i < N_EDGES) {
    int s, d;
    if (f) { s = e[2 * i]; d = e[2 * (N_EDGES + i)]; }
    else   { s = e[i];     d = e[N_EDGES + i]; }
    src32[i] = s;
    dst32[i] = d;
    atomicAdd(&deg[d], 1);
  }
}

// ---------------- CSR build ----------------
__global__ void k_block_sums(const int* __restrict__ deg, int* __restrict__ part) {
  __shared__ int sd[256];
  int i = blockIdx.x * 256 + threadIdx.x;
  sd[threadIdx.x] = (i < N_NODES) ? deg[i] : 0;
  __syncthreads();
  for (int o = 128; o > 0; o >>= 1) {
    if (threadIdx.x < o) sd[threadIdx.x] += sd[threadIdx.x + o];
    __syncthreads();
  }
  if (threadIdx.x == 0) part[blockIdx.x] = sd[0];
}
__global__ void k_scan_part(int* part, int nb) {
  __shared__ int s[256];
  int t = threadIdx.x;
  int v = (t < nb) ? part[t] : 0;
  s[t] = v;
  __syncthreads();
  for (int o = 1; o < 256; o <<= 1) {
    int x = (t >= o) ? s[t - o] : 0;
    __syncthreads();
    s[t] += x;
    __syncthreads();
  }
  if (t < nb) part[t] = s[t] - v;
}
__global__ void k_scan_apply(const int* __restrict__ deg, const int* __restrict__ part,
                             int* __restrict__ roff, int* __restrict__ cursor,
                             float* __restrict__ dinv) {
  __shared__ int s[256];
  int t = threadIdx.x;
  int i = blockIdx.x * 256 + t;
  int v = (i < N_NODES) ? deg[i] : 0;
  s[t] = v;
  __syncthreads();
  for (int o = 1; o < 256; o <<= 1) {
    int x = (t >= o) ? s[t - o] : 0;
    __syncthreads();
    s[t] += x;
    __syncthreads();
  }
  int off = part[blockIdx.x] + s[t] - v;
  if (i < N_NODES) {
    roff[i] = off;
    cursor[i] = off;
    dinv[i] = rsqrtf((float)v + 1.f);
    if (i == N_NODES - 1) roff[N_NODES] = off + v;
  }
}
// fill CSR slots: adj=src, eds=dst, en=dinv[src]
__global__ void k_fill(const int* __restrict__ src, const int* __restrict__ dst,
                       int* __restrict__ cursor, int* __restrict__ adj,
                       int* __restrict__ eds, const float* __restrict__ dinv,
                       float* __restrict__ en) {
  int e = blockIdx.x * 256 + threadIdx.x;
  if (e < N_EDGES) {
    int s = src[e], d = dst[e];
    int pos = atomicAdd(&cursor[d], 1);
    adj[pos] = s;
    eds[pos] = d;
    en[pos] = dinv[s];
  }
}

// ------------- fused prep: 4 weight transposes (bf16) + 2 BN affines -------------
__global__ void k_prep(const float* __restrict__ W1, const float* __restrict__ WG1,
                       const float* __restrict__ W2, const float* __restrict__ WG2,
                       unsigned short* __restrict__ Wt1, unsigned short* __restrict__ WtG1,
                       unsigned short* __restrict__ Wt2, unsigned short* __restrict__ WtG2,
                       const float* b1, const float* g1, const float* be1, const float* m1,
                       const float* v1, const float* b2, const float* g2, const float* be2,
                       const float* m2, const float* v2, float* sc1, float* sh1, float* sc2,
                       float* sh2) {
  int i = blockIdx.x * 256 + threadIdx.x;
  if (i < 16384) {
    int k = i >> 7, c = i & 127;
    Wt1[c * 128 + k] = f2b(W1[i]);
  } else if (i < 49152) {
    int l = i - 16384;
    int k = l >> 8, c = l & 255;
    WtG1[c * 128 + k] = f2b(WG1[l]);
  } else if (i < 65536) {
    int l = i - 49152;
    int k = l >> 7, c = l & 127;
    Wt2[c * 128 + k] = f2b(W2[l]);
  } else if (i < 81920) {
    int l = i - 65536;
    int k = l >> 7, c = l & 127;
    WtG2[c * 128 + k] = f2b(WG2[l]);
  } else if (i < 82048) {
    int c = i - 81920;
    float s = g1[c] * rsqrtf(v1[c] + 1e-5f);
    sc1[c] = s;
    sh1[c] = (b1[c] - m1[c]) * s + be1[c];
  } else if (i < 82176) {
    int c = i - 82048;
    float s = g2[c] * rsqrtf(v2[c] + 1e-5f);
    sc2[c] = s;
    sh2[c] = (b2[c] - m2[c]) * s + be2[c];
  }
}

// 4-channel loader: fp32 or packed-bf16 source
__device__ __forceinline__ float4 ld4(const float* X, size_t idx) {
  return *(const float4*)(X + idx);
}
__device__ __forceinline__ float4 ld4(const unsigned short* X, size_t idx) {
  uint2 r = *(const uint2*)(X + idx);
  return make_float4(blo(r.x), bhi(r.x), blo(r.y), bhi(r.y));
}

// ---------------- MFMA GEMM: Hb[n,C] = bf16( T(X[n,128]) @ W[128,C] ) ----------
// T: 0=identity, 1=relu, 2=relu(affine). 64 rows/block, wave = 16 rows x C cols.
// AL=1: emit GAT logits als/ald straight from the fp32 accumulator registers.
template <int C, int AL, typename TX>
__global__ __launch_bounds__(256) void gemm_mfma(const TX* __restrict__ X,
                                                 const unsigned short* __restrict__ Wt,
                                                 unsigned short* __restrict__ Hb,
                                                 const float* __restrict__ scale,
                                                 const float* __restrict__ shift, int mode,
                                                 const float* __restrict__ a_src,
                                                 const float* __restrict__ a_dst,
                                                 float* __restrict__ als,
                                                 float* __restrict__ ald) {
  __shared__ __align__(16) short smem[(C == 256) ? 16384 : 8704];
  int tid = threadIdx.x;
  int row0 = blockIdx.x * 64;
  for (int i = tid; i < 2048; i += 256) {
    int r = i >> 5;
    int k4 = (i & 31) * 4;
    int row = row0 + r;
    float4 v = make_float4(0.f, 0.f, 0.f, 0.f);
    if (row < N_NODES) v = ld4(X, (size_t)row * 128 + k4);
    if (mode == 2) {
      v.x = v.x * scale[k4] + shift[k4];
      v.y = v.y * scale[k4 + 1] + shift[k4 + 1];
      v.z = v.z * scale[k4 + 2] + shift[k4 + 2];
      v.w = v.w * scale[k4 + 3] + shift[k4 + 3];
    }
    if (mode >= 1) {
      v.x = fmaxf(v.x, 0.f); v.y = fmaxf(v.y, 0.f);
      v.z = fmaxf(v.z, 0.f); v.w = fmaxf(v.w, 0.f);
    }
    uint2 p;
    p.x = (unsigned int)f2b(v.x) | ((unsigned int)f2b(v.y) << 16);
    p.y = (unsigned int)f2b(v.z) | ((unsigned int)f2b(v.w) << 16);
    *(uint2*)&smem[r * 136 + k4] = p;
  }
  __syncthreads();
  int wave = tid >> 6, lane = tid & 63;
  int m = lane & 15, quad = lane >> 4;
  int rl0 = wave * 16;
  bf16x8 a[4];
#pragma unroll
  for (int kk = 0; kk < 4; ++kk)
    a[kk] = *(const bf16x8*)&smem[(rl0 + m) * 136 + kk * 32 + quad * 8];
  f32x4 acc[C / 16];
#pragma unroll
  for (int ct = 0; ct < C / 16; ++ct) acc[ct] = (f32x4){0.f, 0.f, 0.f, 0.f};
#pragma unroll
  for (int ct = 0; ct < C / 16; ++ct) {
    const unsigned short* wp = Wt + (size_t)(ct * 16 + m) * 128 + quad * 8;
#pragma unroll
    for (int kk = 0; kk < 4; ++kk) {
      bf16x8 b = *(const bf16x8*)(wp + kk * 32);
      acc[ct] = __builtin_amdgcn_mfma_f32_16x16x32_bf16(a[kk], b, acc[ct], 0, 0, 0);
    }
  }
  if (AL) {
    float s0[4] = {0.f, 0.f, 0.f, 0.f}, s1[4] = {0.f, 0.f, 0.f, 0.f};
    float d0[4] = {0.f, 0.f, 0.f, 0.f}, d1[4] = {0.f, 0.f, 0.f, 0.f};
#pragma unroll
    for (int ct = 0; ct < C / 16; ++ct) {
      float as = a_src[ct * 16 + m];
      float ad = a_dst[ct * 16 + m];
#pragma unroll
      for (int reg = 0; reg < 4; ++reg) {
        float v = acc[ct][reg];
        if (ct < C / 32) {
          s0[reg] = fmaf(v, as, s0[reg]);
          d0[reg] = fmaf(v, ad, d0[reg]);
        } else {
          s1[reg] = fmaf(v, as, s1[reg]);
          d1[reg] = fmaf(v, ad, d1[reg]);
        }
      }
    }
#pragma unroll
    for (int mask = 1; mask <= 8; mask <<= 1) {
#pragma unroll
      for (int reg = 0; reg < 4; ++reg) {
        s0[reg] += __shfl_xor(s0[reg], mask, 64);
        s1[reg] += __shfl_xor(s1[reg], mask, 64);
        d0[reg] += __shfl_xor(d0[reg], mask, 64);
        d1[reg] += __shfl_xor(d1[reg], mask, 64);
      }
    }
    int reg = m & 3, hsel = (m >> 2) & 1, dsel = m >> 3;
    float sv = hsel ? pick4(s1[0], s1[1], s1[2], s1[3], reg)
                    : pick4(s0[0], s0[1], s0[2], s0[3], reg);
    float dv = hsel ? pick4(d1[0], d1[1], d1[2], d1[3], reg)
                    : pick4(d0[0], d0[1], d0[2], d0[3], reg);
    int row = row0 + rl0 + quad * 4 + reg;
    if (row < N_NODES) {
      float* dst = dsel ? ald : als;
      dst[2 * row + hsel] = dsel ? dv : sv;
    }
  }
  __syncthreads();
#pragma unroll
  for (int ct = 0; ct < C / 16; ++ct) {
#pragma unroll
    for (int reg = 0; reg < 4; ++reg) {
      int rl = rl0 + quad * 4 + reg;
      smem[rl * C + ct * 16 + m] = (short)f2b(acc[ct][reg]);
    }
  }
  __syncthreads();
  for (int i = tid; i < 8 * C; i += 256) {
    int row = row0 + (i * 8) / C;
    if (row < N_NODES)
      *(uint4*)((char*)Hb + (size_t)row0 * C * 2 + (size_t)i * 16) =
          *(uint4*)((char*)smem + (size_t)i * 16);
  }
}

// ---- GCN aggregation: 4 nodes per wave (16 lanes x 16B = 256B node row),
// ---- per-quarter loop: 8/4-wide unmasked + scalar tail, bf16 I/O ----
__global__ __launch_bounds__(256) void gcn_pull(const unsigned short* __restrict__ Hb,
                                                const int* __restrict__ adj,
                                                const int* __restrict__ roff,
                                                const float* __restrict__ en,
                                                const float* __restrict__ dinv,
                                                unsigned short* __restrict__ out) {
  int wv = (blockIdx.x * 256 + threadIdx.x) >> 6;
  int lane = threadIdx.x & 63;
  int q4 = lane >> 4, l16 = lane & 15;
  int i = 4 * wv + q4;
  if (i >= N_NODES) return;  // exec-masked quarter-exit
  int off = roff[i], end = roff[i + 1];
  float di = dinv[i];
  uint4 u = *(const uint4*)(Hb + (size_t)i * 128 + l16 * 8);
  float a0 = blo(u.x) * di, a1 = bhi(u.x) * di;
  float a2 = blo(u.y) * di, a3 = bhi(u.y) * di;
  float a4 = blo(u.z) * di, a5 = bhi(u.z) * di;
  float a6 = blo(u.w) * di, a7 = bhi(u.w) * di;  // self-loop
  int j = off;
  for (; j + 8 <= end; j += 8) {  // 8 gathers in flight
    int ss[8]; float ww[8]; uint4 vv[8];
#pragma unroll
    for (int k = 0; k < 8; ++k) { ss[k] = adj[j + k]; ww[k] = en[j + k]; }
#pragma unroll
    for (int k = 0; k < 8; ++k)
      vv[k] = *(const uint4*)(Hb + (size_t)ss[k] * 128 + l16 * 8);
#pragma unroll
    for (int k = 0; k < 8; ++k) {
      a0 = fmaf(blo(vv[k].x), ww[k], a0); a1 = fmaf(bhi(vv[k].x), ww[k], a1);
      a2 = fmaf(blo(vv[k].y), ww[k], a2); a3 = fmaf(bhi(vv[k].y), ww[k], a3);
      a4 = fmaf(blo(vv[k].z), ww[k], a4); a5 = fmaf(bhi(vv[k].z), ww[k], a5);
      a6 = fmaf(blo(vv[k].w), ww[k], a6); a7 = fmaf(bhi(vv[k].w), ww[k], a7);
    }
  }
  for (; j + 4 <= end; j += 4) {
    int ss[4]; float ww[4]; uint4 vv[4];
#pragma unroll
    for (int k = 0; k < 4; ++k) { ss[k] = adj[j + k]; ww[k] = en[j + k]; }
#pragma unroll
    for (int k = 0; k < 4; ++k)
      vv[k] = *(const uint4*)(Hb + (size_t)ss[k] * 128 + l16 * 8);
#pragma unroll
    for (int k = 0; k < 4; ++k) {
      a0 = fmaf(blo(vv[k].x), ww[k], a0); a1 = fmaf(bhi(vv[k].x), ww[k], a1);
      a2 = fmaf(blo(vv[k].y), ww[k], a2); a3 = fmaf(bhi(vv[k].y), ww[k], a3);
      a4 = fmaf(blo(vv[k].z), ww[k], a4); a5 = fmaf(bhi(vv[k].z), ww[k], a5);
      a6 = fmaf(blo(vv[k].w), ww[k], a6); a7 = fmaf(bhi(vv[k].w), ww[k], a7);
    }
  }
  for (; j < end; ++j) {
    int s = adj[j];
    float w = en[j];
    uint4 v = *(const uint4*)(Hb + (size_t)s * 128 + l16 * 8);
    a0 = fmaf(blo(v.x), w, a0); a1 = fmaf(bhi(v.x), w, a1);
    a2 = fmaf(blo(v.y), w, a2); a3 = fmaf(bhi(v.y), w, a3);
    a4 = fmaf(blo(v.z), w, a4); a5 = fmaf(bhi(v.z), w, a5);
    a6 = fmaf(blo(v.w), w, a6); a7 = fmaf(bhi(v.w), w, a7);
  }
  uint4 pw;
  pw.x = (unsigned int)f2b(a0 * di) | ((unsigned int)f2b(a1 * di) << 16);
  pw.y = (unsigned int)f2b(a2 * di) | ((unsigned int)f2b(a3 * di) << 16);
  pw.z = (unsigned int)f2b(a4 * di) | ((unsigned int)f2b(a5 * di) << 16);
  pw.w = (unsigned int)f2b(a6 * di) | ((unsigned int)f2b(a7 * di) << 16);
  *(uint4*)(out + (size_t)i * 128 + l16 * 8) = pw;
}

// ------------- per-edge exp(leaky(...)) precompute (edge-parallel) -------------
__global__ void gat_ew(const int* __restrict__ adj, const int* __restrict__ eds,
                       const float* __restrict__ als, const float* __restrict__ ald,
                       float2* __restrict__ ew) {
  int j = blockIdx.x * 256 + threadIdx.x;
  if (j >= N_EDGES) return;
  int s = adj[j], d = eds[j];
  float2 a = *(const float2*)(als + 2 * s);
  float2 b = *(const float2*)(ald + 2 * d);
  ew[j] = make_float2(__expf(leaky(a.x + b.x)), __expf(leaky(a.y + b.y)));
}

// -------- GAT aggregation HD=128: 1 node/wave (r10-proven), single pass
// -------- (unnormalized sum + raw-weight denominator), 8/4-wide + scalar tail ----
__global__ __launch_bounds__(256) void gat_pull128(const unsigned short* __restrict__ Hb,
                                                   const int* __restrict__ adj,
                                                   const int* __restrict__ roff,
                                                   const float2* __restrict__ ew,
                                                   const float* __restrict__ als,
                                                   const float* __restrict__ ald,
                                                   const float* __restrict__ bias,
                                                   unsigned short* __restrict__ out) {
  int wid = (blockIdx.x * 256 + threadIdx.x) >> 6;
  int lane = threadIdx.x & 63;
  if (wid >= N_NODES) return;
  int i = wid;
  int off = roff[i], end = roff[i + 1];
  int head = lane >> 5;
  float p0 = 0.f, p1 = 0.f;  // raw-weight sums (identical across lanes)
  float acc0 = 0.f, acc1 = 0.f, acc2 = 0.f, acc3 = 0.f;  // unnormalized
  int j = off;
  for (; j + 8 <= end; j += 8) {
    int ss[8]; float qq[8]; uint2 vv[8];
#pragma unroll
    for (int k = 0; k < 8; ++k) {
      ss[k] = __builtin_amdgcn_readfirstlane(adj[j + k]);
      float2 w = ew[j + k];
      p0 += w.x; p1 += w.y;
      qq[k] = head ? w.y : w.x;
    }
#pragma unroll
    for (int k = 0; k < 8; ++k)
      vv[k] = *(const uint2*)(Hb + (size_t)ss[k] * 256 + lane * 4);
#pragma unroll
    for (int k = 0; k < 8; ++k) {
      acc0 = fmaf(qq[k], blo(vv[k].x), acc0);
      acc1 = fmaf(qq[k], bhi(vv[k].x), acc1);
      acc2 = fmaf(qq[k], blo(vv[k].y), acc2);
      acc3 = fmaf(qq[k], bhi(vv[k].y), acc3);
    }
  }
  for (; j + 4 <= end; j += 4) {
    int s0 = __builtin_amdgcn_readfirstlane(adj[j]);
    int s1 = __builtin_amdgcn_readfirstlane(adj[j + 1]);
    int s2 = __builtin_amdgcn_readfirstlane(adj[j + 2]);
    int s3 = __builtin_amdgcn_readfirstlane(adj[j + 3]);
    float2 w0 = ew[j], w1 = ew[j + 1], w2 = ew[j + 2], w3 = ew[j + 3];
    p0 += w0.x + w1.x + w2.x + w3.x;
    p1 += w0.y + w1.y + w2.y + w3.y;
    uint2 v0 = *(const uint2*)(Hb + (size_t)s0 * 256 + lane * 4);
    uint2 v1 = *(const uint2*)(Hb + (size_t)s1 * 256 + lane * 4);
    uint2 v2 = *(const uint2*)(Hb + (size_t)s2 * 256 + lane * 4);
    uint2 v3 = *(const uint2*)(Hb + (size_t)s3 * 256 + lane * 4);
    float q0 = head ? w0.y : w0.x;
    float q1 = head ? w1.y : w1.x;
    float q2 = head ? w2.y : w2.x;
    float q3 = head ? w3.y : w3.x;
    acc0 = fmaf(q0, blo(v0.x), acc0); acc1 = fmaf(q0, bhi(v0.x), acc1);
    acc2 = fmaf(q0, blo(v0.y), acc2); acc3 = fmaf(q0, bhi(v0.y), acc3);
    acc0 = fmaf(q1, blo(v1.x), acc0); acc1 = fmaf(q1, bhi(v1.x), acc1);
    acc2 = fmaf(q1, blo(v1.y), acc2); acc3 = fmaf(q1, bhi(v1.y), acc3);
    acc0 = fmaf(q2, blo(v2.x), acc0); acc1 = fmaf(q2, bhi(v2.x), acc1);
    acc2 = fmaf(q2, blo(v2.y), acc2); acc3 = fmaf(q2, bhi(v2.y), acc3);
    acc0 = fmaf(q3, blo(v3.x), acc0); acc1 = fmaf(q3, bhi(v3.x), acc1);
    acc2 = fmaf(q3, blo(v3.y), acc2); acc3 = fmaf(q3, bhi(v3.y), acc3);
  }
  for (; j < end; ++j) {
    int s = __builtin_amdgcn_readfirstlane(adj[j]);
    float2 w = ew[j];
    p0 += w.x; p1 += w.y;
    float q = head ? w.y : w.x;
    uint2 v = *(const uint2*)(Hb + (size_t)s * 256 + lane * 4);
    acc0 = fmaf(q, blo(v.x), acc0);
    acc1 = fmaf(q, bhi(v.x), acc1);
    acc2 = fmaf(q, blo(v.y), acc2);
    acc3 = fmaf(q, bhi(v.y), acc3);
  }
  // self-loop + normalization
  float2 ai = *(const float2*)(als + 2 * i);
  float2 di = *(const float2*)(ald + 2 * i);
  float es0 = __expf(leaky(ai.x + di.x));
  float es1 = __expf(leaky(ai.y + di.y));
  float rsel = head ? (0.5f / (p1 + es1)) : (0.5f / (p0 + es0));  // 0.5 = head mean
  float wself = head ? es1 : es0;
  uint2 u = *(const uint2*)(Hb + (size_t)i * 256 + lane * 4);
  acc0 = (acc0 + wself * blo(u.x)) * rsel;
  acc1 = (acc1 + wself * bhi(u.x)) * rsel;
  acc2 = (acc2 + wself * blo(u.y)) * rsel;
  acc3 = (acc3 + wself * bhi(u.y)) * rsel;
  acc0 += __shfl_xor(acc0, 32, 64);
  acc1 += __shfl_xor(acc1, 32, 64);
  acc2 += __shfl_xor(acc2, 32, 64);
  acc3 += __shfl_xor(acc3, 32, 64);
  if (lane < 32) {
    int c = lane * 4;
    uint2 pw;
    pw.x = (unsigned int)f2b(acc0 + bias[c]) | ((unsigned int)f2b(acc1 + bias[c + 1]) << 16);
    pw.y = (unsigned int)f2b(acc2 + bias[c + 2]) | ((unsigned int)f2b(acc3 + bias[c + 3]) << 16);
    *(uint2*)(out + (size_t)i * 128 + c) = pw;
  }
}

// ---- GAT HD=64 + fused log_softmax: 4 nodes/wave (16 lanes x 16B = 256B row),
// ---- single pass, 8/4-wide unmasked + scalar tail.
// ---- Within a node's 16 lanes: lanes 0-7 = head0 ch[8p..8p+7], 8-15 = head1.
__global__ __launch_bounds__(256) void gat_pull64_lsm(const unsigned short* __restrict__ Hb,
                                                      const int* __restrict__ adj,
                                                      const int* __restrict__ roff,
                                                      const float2* __restrict__ ew,
                                                      const float* __restrict__ als,
                                                      const float* __restrict__ ald,
                                                      const float* __restrict__ bias,
                                                      float* __restrict__ out) {
  int wv = (blockIdx.x * 256 + threadIdx.x) >> 6;
  int lane = threadIdx.x & 63;
  int q4 = lane >> 4, l16 = lane & 15;
  int hh = l16 >> 3, p = l16 & 7;  // sub-head and channel-octet within node group
  int i = 4 * wv + q4;
  if (i >= N_NODES) return;
  int off = roff[i], end = roff[i + 1];
  int cbase = hh * 64 + 8 * p;  // channel offset within this node's 128-ch row
  float p0 = 0.f, p1 = 0.f;
  float acc0 = 0.f, acc1 = 0.f, acc2 = 0.f, acc3 = 0.f;
  float acc4 = 0.f, acc5 = 0.f, acc6 = 0.f, acc7 = 0.f;
  int j = off;
  for (; j + 8 <= end; j += 8) {
    int ss[8]; float qq[8]; uint4 vv[8];
#pragma unroll
    for (int k = 0; k < 8; ++k) {
      ss[k] = adj[j + k];
      float2 w = ew[j + k];
      p0 += w.x; p1 += w.y;
      qq[k] = hh ? w.y : w.x;
    }
#pragma unroll
    for (int k = 0; k < 8; ++k)
      vv[k] = *(const uint4*)(Hb + (size_t)ss[k] * 128 + cbase);
#pragma unroll
    for (int k = 0; k < 8; ++k) {
      acc0 = fmaf(qq[k], blo(vv[k].x), acc0); acc1 = fmaf(qq[k], bhi(vv[k].x), acc1);
      acc2 = fmaf(qq[k], blo(vv[k].y), acc2); acc3 = fmaf(qq[k], bhi(vv[k].y), acc3);
      acc4 = fmaf(qq[k], blo(vv[k].z), acc4); acc5 = fmaf(qq[k], bhi(vv[k].z), acc5);
      acc6 = fmaf(qq[k], blo(vv[k].w), acc6); acc7 = fmaf(qq[k], bhi(vv[k].w), acc7);
    }
  }
  for (; j + 4 <= end; j += 4) {
    int ss[4]; float qq[4]; uint4 vv[4];
#pragma unroll
    for (int k = 0; k < 4; ++k) {
      ss[k] = adj[j + k];
      float2 w = ew[j + k];
      p0 += w.x; p1 += w.y;
      qq[k] = hh ? w.y : w.x;
    }
#pragma unroll
    for (int k = 0; k < 4; ++k)
      vv[k] = *(const uint4*)(Hb + (size_t)ss[k] * 128 + cbase);
#pragma unroll
    for (int k = 0; k < 4; ++k) {
      acc0 = fmaf(qq[k], blo(vv[k].x), acc0); acc1 = fmaf(qq[k], bhi(vv[k].x), acc1);
      acc2 = fmaf(qq[k], blo(vv[k].y), acc2); acc3 = fmaf(qq[k], bhi(vv[k].y), acc3);
      acc4 = fmaf(qq[k], blo(vv[k].z), acc4); acc5 = fmaf(qq[k], bhi(vv[k].z), acc5);
      acc6 = fmaf(qq[k], blo(vv[k].w), acc6); acc7 = fmaf(qq[k], bhi(vv[k].w), acc7);
    }
  }
  for (; j < end; ++j) {
    int s = adj[j];
    float2 w = ew[j];
    p0 += w.x; p1 += w.y;
    float q = hh ? w.y : w.x;
    uint4 v = *(const uint4*)(Hb + (size_t)s * 128 + cbase);
    acc0 = fmaf(q, blo(v.x), acc0); acc1 = fmaf(q, bhi(v.x), acc1);
    acc2 = fmaf(q, blo(v.y), acc2); acc3 = fmaf(q, bhi(v.y), acc3);
    acc4 = fmaf(q, blo(v.z), acc4); acc5 = fmaf(q, bhi(v.z), acc5);
    acc6 = fmaf(q, blo(v.w), acc6); acc7 = fmaf(q, bhi(v.w), acc7);
  }
  // self-loop + normalization
  float2 ai = *(const float2*)(als + 2 * i);
  float2 dd = *(const float2*)(ald + 2 * i);
  float es0 = __expf(leaky(ai.x + dd.x));
  float es1 = __expf(leaky(ai.y + dd.y));
  float rsel = hh ? (0.5f / (p1 + es1)) : (0.5f / (p0 + es0));
  float wself = hh ? es1 : es0;
  uint4 u = *(const uint4*)(Hb + (size_t)i * 128 + cbase);
  acc0 = (acc0 + wself * blo(u.x)) * rsel; acc1 = (acc1 + wself * bhi(u.x)) * rsel;
  acc2 = (acc2 + wself * blo(u.y)) * rsel; acc3 = (acc3 + wself * bhi(u.y)) * rsel;
  acc4 = (acc4 + wself * blo(u.z)) * rsel; acc5 = (acc5 + wself * bhi(u.z)) * rsel;
  acc6 = (acc6 + wself * blo(u.w)) * rsel; acc7 = (acc7 + wself * bhi(u.w)) * rsel;
  // head combine: lane p (head0 ch 8p..) + lane 8+p (head1 ch 8p..)
  acc0 += __shfl_xor(acc0, 8, 64); acc1 += __shfl_xor(acc1, 8, 64);
  acc2 += __shfl_xor(acc2, 8, 64); acc3 += __shfl_xor(acc3, 8, 64);
  acc4 += __shfl_xor(acc4, 8, 64); acc5 += __shfl_xor(acc5, 8, 64);
  acc6 += __shfl_xor(acc6, 8, 64); acc7 += __shfl_xor(acc7, 8, 64);
  float4 b0 = *(const float4*)(bias + 8 * p);
  float4 b1 = *(const float4*)(bias + 8 * p + 4);
  float v0 = acc0 + b0.x, v1 = acc1 + b0.y, v2 = acc2 + b0.z, v3 = acc3 + b0.w;
  float v4 = acc4 + b1.x, v5 = acc5 + b1.y, v6 = acc6 + b1.z, v7 = acc7 + b1.w;
  // log_softmax over 64 ch = 8 lanes x 8 vals (lanes 8-15 hold identical sums)
  float mv = fmaxf(fmaxf(fmaxf(v0, v1), fmaxf(v2, v3)),
                   fmaxf(fmaxf(v4, v5), fmaxf(v6, v7)));
#pragma unroll
  for (int mm = 4; mm > 0; mm >>= 1) mv = fmaxf(mv, __shfl_xor(mv, mm, 64));
  float sv = __expf(v0 - mv) + __expf(v1 - mv) + __expf(v2 - mv) + __expf(v3 - mv) +
             __expf(v4 - mv) + __expf(v5 - mv) + __expf(v6 - mv) + __expf(v7 - mv);
#pragma unroll
  for (int mm = 4; mm > 0; mm >>= 1) sv += __shfl_xor(sv, mm, 64);
  float ls = mv + __logf(sv);
  if (hh == 0) {
    *(float4*)(out + (size_t)i * 64 + 8 * p) =
        make_float4(v0 - ls, v1 - ls, v2 - ls, v3 - ls);
    *(float4*)(out + (size_t)i * 64 + 8 * p + 4) =
        make_float4(v4 - ls, v5 - ls, v6 - ls, v7 - ls);
  }
}

extern "C" void kernel_launch(void* const* d_in, const int* in_sizes, int n_in, void* d_out,
                              int out_size, void* d_ws, size_t ws_size, hipStream_t stream) {
  const float* x      = (const float*)d_in[0];
  const int* eidx     = (const int*)d_in[1];
  const float* W_gcn1 = (const float*)d_in[2];
  const float* b_gcn1 = (const float*)d_in[3];
  const float* bn1_g  = (const float*)d_in[4];
  const float* bn1_b  = (const float*)d_in[5];
  const float* bn1_m  = (const float*)d_in[6];
  const float* bn1_v  = (const float*)d_in[7];
  const float* W_gat1 = (const float*)d_in[8];
  const float* a_src1 = (const float*)d_in[9];
  const float* a_dst1 = (const float*)d_in[10];
  const float* b_gat1 = (const float*)d_in[11];
  const float* W_gcn2 = (const float*)d_in[12];
  const float* b_gcn2 = (const float*)d_in[13];
  const float* bn2_g  = (const float*)d_in[14];
  const float* bn2_b  = (const float*)d_in[15];
  const float* bn2_m  = (const float*)d_in[16];
  const float* bn2_v  = (const float*)d_in[17];
  const float* W_gat2 = (const float*)d_in[18];
  const float* a_src2 = (const float*)d_in[19];
  const float* a_dst2 = (const float*)d_in[20];
  const float* b_gat2 = (const float*)d_in[21];

  char* ws = (char*)d_ws;
  size_t o = 0;
  auto take = [&](size_t bytes) {
    char* p = ws + o;
    o = (o + bytes + 255) & ~(size_t)255;
    return p;
  };
  int* srcs    = (int*)take((size_t)N_EDGES * 4);
  int* dstsb   = (int*)take((size_t)N_EDGES * 4);
  int* deg     = (int*)take((size_t)N_NODES * 4);
  int* roff    = (int*)take((size_t)(N_NODES + 1) * 4);
  int* cursor  = (int*)take((size_t)N_NODES * 4);
  int* adj     = (int*)take((size_t)N_EDGES * 4);
  int* eds     = (int*)take((size_t)N_EDGES * 4);
  float* en    = (float*)take((size_t)N_EDGES * 4);
  float2* ew   = (float2*)take((size_t)N_EDGES * 8);
  float* dinv  = (float*)take((size_t)N_NODES * 4);
  float* als   = (float*)take((size_t)2 * N_NODES * 4);
  float* ald   = (float*)take((size_t)2 * N_NODES * 4);
  float* sc1   = (float*)take(128 * 4);
  float* sh1   = (float*)take(128 * 4);
  float* sc2   = (float*)take(128 * 4);
  float* sh2   = (float*)take(128 * 4);
  int* part    = (int*)take(256 * 4);
  unsigned short* Wt1  = (unsigned short*)take((size_t)128 * 128 * 2);
  unsigned short* WtG1 = (unsigned short*)take((size_t)256 * 128 * 2);
  unsigned short* Wt2  = (unsigned short*)take((size_t)128 * 128 * 2);
  unsigned short* WtG2 = (unsigned short*)take((size_t)128 * 128 * 2);
  unsigned short* Hb   = (unsigned short*)take((size_t)N_NODES * 256 * 2);
  unsigned short* Pb   = (unsigned short*)take((size_t)N_NODES * 128 * 2);
  (void)ws_size; (void)in_sizes; (void)n_in; (void)out_size;

  int eb = (N_EDGES + 255) / 256;
  int nb = (N_NODES + 255) / 256;
  int wb = (N_NODES + 3) / 4;              // wave per node (gat_pull128)
  int qb = ((N_NODES + 3) / 4 + 3) / 4;    // wave per 4 nodes (gcn_pull, lsm)
  int gb = (N_NODES + 63) / 64;            // MFMA-GEMM blocks

  // CSR build + prep
  hipMemsetAsync(deg, 0, (size_t)N_NODES * 4, stream);
  k_convert<<<eb, 256, 0, stream>>>(eidx, srcs, dstsb, deg);
  k_block_sums<<<nb, 256, 0, stream>>>(deg, part);
  k_scan_part<<<1, 256, 0, stream>>>(part, nb);
  k_scan_apply<<<nb, 256, 0, stream>>>(deg, part, roff, cursor, dinv);
  k_fill<<<eb, 256, 0, stream>>>(srcs, dstsb, cursor, adj, eds, dinv, en);
  k_prep<<<321, 256, 0, stream>>>(W_gcn1, W_gat1, W_gcn2, W_gat2, Wt1, WtG1, Wt2, WtG2,
                                  b_gcn1, bn1_g, bn1_b, bn1_m, bn1_v, b_gcn2, bn2_g, bn2_b,
                                  bn2_m, bn2_v, sc1, sh1, sc2, sh2);

  // Layer pipeline (all intermediates bf16; gat_al fused into GEMM epilogues)
  gemm_mfma<128, 0><<<gb, 256, 0, stream>>>(x, Wt1, Hb, (const float*)nullptr,
                                            (const float*)nullptr, 0, nullptr, nullptr,
                                            nullptr, nullptr);
  gcn_pull<<<qb, 256, 0, stream>>>(Hb, adj, roff, en, dinv, Pb);
  gemm_mfma<256, 1><<<gb, 256, 0, stream>>>(Pb, WtG1, Hb, sc1, sh1, 2, a_src1, a_dst1,
                                            als, ald);
  gat_ew<<<eb, 256, 0, stream>>>(adj, eds, als, ald, ew);
  gat_pull128<<<wb, 256, 0, stream>>>(Hb, adj, roff, ew, als, ald, b_gat1, Pb);
  gemm_mfma<128, 0><<<gb, 256, 0, stream>>>(Pb, Wt2, Hb, (const float*)nullptr,
                                            (const float*)nullptr, 1, nullptr, nullptr,
                                            nullptr, nullptr);
  gcn_pull<<<qb, 256, 0, stream>>>(Hb, adj, roff, en, dinv, Pb);
  gemm_mfma<128, 1><<<gb, 256, 0, stream>>>(Pb, WtG2, Hb, sc2, sh2, 2, a_src2, a_dst2,
                                            als, ald);
  gat_ew<<<eb, 256, 0, stream>>>(adj, eds, als, ald, ew);
  gat_pull64_lsm<<<qb, 256, 0, stream>>>(Hb, adj, roff, ew, als, ald, b_gat2, (float*)d_out);
}

// Round 13
// 439.659 us; speedup vs baseline: 1.0115x; 1.0115x over previous
//
#include <hip/hip_runtime.h>
#include <hip/hip_bf16.h>

#define N_NODES 50000
#define N_EDGES 600000

typedef short bf16x8 __attribute__((ext_vector_type(8)));
typedef float f32x4 __attribute__((ext_vector_type(4)));

__device__ __forceinline__ float leaky(float e) { return e > 0.f ? e : 0.2f * e; }
__device__ __forceinline__ unsigned short f2b(float f) {
  __hip_bfloat16 h = __float2bfloat16(f);
  return *reinterpret_cast<unsigned short*>(&h);
}
__device__ __forceinline__ float blo(unsigned int u) { return __uint_as_float(u << 16); }
__device__ __forceinline__ float bhi(unsigned int u) { return __uint_as_float(u & 0xffff0000u); }
__device__ __forceinline__ float pick4(float a0, float a1, float a2, float a3, int r) {
  float x = (r & 1) ? a1 : a0;
  float y = (r & 1) ? a3 : a2;
  return (r & 2) ? y : x;
}

// ------- edge convert (detect int64 vs int32) + degree count + weight prep -------
__global__ void k_convert(const int* __restrict__ e, int* __restrict__ src32,
                          int* __restrict__ dst32, int* __restrict__ deg,
                          const float* __restrict__ W1, const float* __restrict__ WG1,
                          const float* __restrict__ W2, const float* __restrict__ WG2,
                          unsigned short* __restrict__ Wt1, unsigned short* __restrict__ WtG1,
                          unsigned short* __restrict__ Wt2, unsigned short* __restrict__ WtG2,
                          const float* b1, const float* g1, const float* be1, const float* m1,
                          const float* v1, const float* b2, const float* g2, const float* be2,
                          const float* m2, const float* v2, float* sc1, float* sh1,
                          float* sc2, float* sh2) {
  __shared__ int sflag;
  int tid = threadIdx.x;
  if (tid < 64) {  // wave 0: sample odd int32 words; all-zero => int64 input
    int idx = 1 + 2 * tid * 4096;
    int v = e[idx];
    unsigned long long nz = __ballot(v != 0);
    if (tid == 0) sflag = (nz == 0ULL) ? 1 : 0;
  }
  __syncthreads();
  int f = sflag;
  int i = blockIdx.x * 256 + tid;
  if (i < N_EDGES) {
    int s, d;
    if (f) { s = e[2 * i]; d = e[2 * (N_EDGES + i)]; }
    else   { s = e[i];     d = e[N_EDGES + i]; }
    src32[i] = s;
    dst32[i] = d;
    atomicAdd(&deg[d], 1);
  }
  // fused prep (independent outputs, same index space)
  if (i < 16384) {
    int k = i >> 7, c = i & 127;
    Wt1[c * 128 + k] = f2b(W1[i]);
  } else if (i < 49152) {
    int l = i - 16384;
    int k = l >> 8, c = l & 255;
    WtG1[c * 128 + k] = f2b(WG1[l]);
  } else if (i < 65536) {
    int l = i - 49152;
    int k = l >> 7, c = l & 127;
    Wt2[c * 128 + k] = f2b(W2[l]);
  } else if (i < 81920) {
    int l = i - 65536;
    int k = l >> 7, c = l & 127;
    WtG2[c * 128 + k] = f2b(WG2[l]);
  } else if (i < 82048) {
    int c = i - 81920;
    float s = g1[c] * rsqrtf(v1[c] + 1e-5f);
    sc1[c] = s;
    sh1[c] = (b1[c] - m1[c]) * s + be1[c];
  } else if (i < 82176) {
    int c = i - 82048;
    float s = g2[c] * rsqrtf(v2[c] + 1e-5f);
    sc2[c] = s;
    sh2[c] = (b2[c] - m2[c]) * s + be2[c];
  }
}

// ---- CSR offsets in one kernel: block-local scan + atomic block base.
// roff is NOT globally monotone (block bases are in atomic order) — consumers
// use end = roff[i] + deg[i], never roff[i+1].
__global__ void k_offsets(const int* __restrict__ deg, int* __restrict__ gbase,
                          int* __restrict__ roff, int* __restrict__ cursor,
                          float* __restrict__ dinv) {
  __shared__ int s[256];
  __shared__ int base;
  int t = threadIdx.x;
  int i = blockIdx.x * 256 + t;
  int v = (i < N_NODES) ? deg[i] : 0;
  s[t] = v;
  __syncthreads();
  for (int o = 1; o < 256; o <<= 1) {
    int x = (t >= o) ? s[t - o] : 0;
    __syncthreads();
    s[t] += x;
    __syncthreads();
  }
  if (t == 255) base = atomicAdd(gbase, s[255]);
  __syncthreads();
  int off = base + s[t] - v;  // exclusive prefix within block + block base
  if (i < N_NODES) {
    roff[i] = off;
    cursor[i] = off;
    dinv[i] = rsqrtf((float)v + 1.f);
  }
}
// fill CSR slots: adj=src, eds=dst, en=dinv[src]
__global__ void k_fill(const int* __restrict__ src, const int* __restrict__ dst,
                       int* __restrict__ cursor, int* __restrict__ adj,
                       int* __restrict__ eds, const float* __restrict__ dinv,
                       float* __restrict__ en) {
  int e = blockIdx.x * 256 + threadIdx.x;
  if (e < N_EDGES) {
    int s = src[e], d = dst[e];
    int pos = atomicAdd(&cursor[d], 1);
    adj[pos] = s;
    eds[pos] = d;
    en[pos] = dinv[s];
  }
}

// 4-channel loader: fp32 or packed-bf16 source
__device__ __forceinline__ float4 ld4(const float* X, size_t idx) {
  return *(const float4*)(X + idx);
}
__device__ __forceinline__ float4 ld4(const unsigned short* X, size_t idx) {
  uint2 r = *(const uint2*)(X + idx);
  return make_float4(blo(r.x), bhi(r.x), blo(r.y), bhi(r.y));
}

// ---------------- MFMA GEMM: Hb[n,C] = bf16( T(X[n,128]) @ W[128,C] ) ----------
// T: 0=identity, 1=relu, 2=relu(affine). 64 rows/block, wave = 16 rows x C cols.
// AL=1: emit GAT logits als/ald straight from the fp32 accumulator registers.
template <int C, int AL, typename TX>
__global__ __launch_bounds__(256) void gemm_mfma(const TX* __restrict__ X,
                                                 const unsigned short* __restrict__ Wt,
                                                 unsigned short* __restrict__ Hb,
                                                 const float* __restrict__ scale,
                                                 const float* __restrict__ shift, int mode,
                                                 const float* __restrict__ a_src,
                                                 const float* __restrict__ a_dst,
                                                 float* __restrict__ als,
                                                 float* __restrict__ ald) {
  __shared__ __align__(16) short smem[(C == 256) ? 16384 : 8704];
  int tid = threadIdx.x;
  int row0 = blockIdx.x * 64;
  for (int i = tid; i < 2048; i += 256) {
    int r = i >> 5;
    int k4 = (i & 31) * 4;
    int row = row0 + r;
    float4 v = make_float4(0.f, 0.f, 0.f, 0.f);
    if (row < N_NODES) v = ld4(X, (size_t)row * 128 + k4);
    if (mode == 2) {
      v.x = v.x * scale[k4] + shift[k4];
      v.y = v.y * scale[k4 + 1] + shift[k4 + 1];
      v.z = v.z * scale[k4 + 2] + shift[k4 + 2];
      v.w = v.w * scale[k4 + 3] + shift[k4 + 3];
    }
    if (mode >= 1) {
      v.x = fmaxf(v.x, 0.f); v.y = fmaxf(v.y, 0.f);
      v.z = fmaxf(v.z, 0.f); v.w = fmaxf(v.w, 0.f);
    }
    uint2 p;
    p.x = (unsigned int)f2b(v.x) | ((unsigned int)f2b(v.y) << 16);
    p.y = (unsigned int)f2b(v.z) | ((unsigned int)f2b(v.w) << 16);
    *(uint2*)&smem[r * 136 + k4] = p;
  }
  __syncthreads();
  int wave = tid >> 6, lane = tid & 63;
  int m = lane & 15, quad = lane >> 4;
  int rl0 = wave * 16;
  bf16x8 a[4];
#pragma unroll
  for (int kk = 0; kk < 4; ++kk)
    a[kk] = *(const bf16x8*)&smem[(rl0 + m) * 136 + kk * 32 + quad * 8];
  f32x4 acc[C / 16];
#pragma unroll
  for (int ct = 0; ct < C / 16; ++ct) acc[ct] = (f32x4){0.f, 0.f, 0.f, 0.f};
#pragma unroll
  for (int ct = 0; ct < C / 16; ++ct) {
    const unsigned short* wp = Wt + (size_t)(ct * 16 + m) * 128 + quad * 8;
#pragma unroll
    for (int kk = 0; kk < 4; ++kk) {
      bf16x8 b = *(const bf16x8*)(wp + kk * 32);
      acc[ct] = __builtin_amdgcn_mfma_f32_16x16x32_bf16(a[kk], b, acc[ct], 0, 0, 0);
    }
  }
  if (AL) {
    float s0[4] = {0.f, 0.f, 0.f, 0.f}, s1[4] = {0.f, 0.f, 0.f, 0.f};
    float d0[4] = {0.f, 0.f, 0.f, 0.f}, d1[4] = {0.f, 0.f, 0.f, 0.f};
#pragma unroll
    for (int ct = 0; ct < C / 16; ++ct) {
      float as = a_src[ct * 16 + m];
      float ad = a_dst[ct * 16 + m];
#pragma unroll
      for (int reg = 0; reg < 4; ++reg) {
        float v = acc[ct][reg];
        if (ct < C / 32) {
          s0[reg] = fmaf(v, as, s0[reg]);
          d0[reg] = fmaf(v, ad, d0[reg]);
        } else {
          s1[reg] = fmaf(v, as, s1[reg]);
          d1[reg] = fmaf(v, ad, d1[reg]);
        }
      }
    }
#pragma unroll
    for (int mask = 1; mask <= 8; mask <<= 1) {
#pragma unroll
      for (int reg = 0; reg < 4; ++reg) {
        s0[reg] += __shfl_xor(s0[reg], mask, 64);
        s1[reg] += __shfl_xor(s1[reg], mask, 64);
        d0[reg] += __shfl_xor(d0[reg], mask, 64);
        d1[reg] += __shfl_xor(d1[reg], mask, 64);
      }
    }
    int reg = m & 3, hsel = (m >> 2) & 1, dsel = m >> 3;
    float sv = hsel ? pick4(s1[0], s1[1], s1[2], s1[3], reg)
                    : pick4(s0[0], s0[1], s0[2], s0[3], reg);
    float dv = hsel ? pick4(d1[0], d1[1], d1[2], d1[3], reg)
                    : pick4(d0[0], d0[1], d0[2], d0[3], reg);
    int row = row0 + rl0 + quad * 4 + reg;
    if (row < N_NODES) {
      float* dst = dsel ? ald : als;
      dst[2 * row + hsel] = dsel ? dv : sv;
    }
  }
  __syncthreads();
#pragma unroll
  for (int ct = 0; ct < C / 16; ++ct) {
#pragma unroll
    for (int reg = 0; reg < 4; ++reg) {
      int rl = rl0 + quad * 4 + reg;
      smem[rl * C + ct * 16 + m] = (short)f2b(acc[ct][reg]);
    }
  }
  __syncthreads();
  for (int i = tid; i < 8 * C; i += 256) {
    int row = row0 + (i * 8) / C;
    if (row < N_NODES)
      *(uint4*)((char*)Hb + (size_t)row0 * C * 2 + (size_t)i * 16) =
          *(uint4*)((char*)smem + (size_t)i * 16);
  }
}

// ---- GCN aggregation: 4 nodes per wave (16 lanes x 16B = 256B node row),
// ---- per-quarter loop: 8/4-wide unmasked + scalar tail, bf16 I/O ----
__global__ __launch_bounds__(256) void gcn_pull(const unsigned short* __restrict__ Hb,
                                                const int* __restrict__ adj,
                                                const int* __restrict__ roff,
                                                const int* __restrict__ deg,
                                                const float* __restrict__ en,
                                                const float* __restrict__ dinv,
                                                unsigned short* __restrict__ out) {
  int wv = (blockIdx.x * 256 + threadIdx.x) >> 6;
  int lane = threadIdx.x & 63;
  int q4 = lane >> 4, l16 = lane & 15;
  int i = 4 * wv + q4;
  if (i >= N_NODES) return;  // exec-masked quarter-exit
  int off = roff[i], end = off + deg[i];
  float di = dinv[i];
  uint4 u = *(const uint4*)(Hb + (size_t)i * 128 + l16 * 8);
  float a0 = blo(u.x) * di, a1 = bhi(u.x) * di;
  float a2 = blo(u.y) * di, a3 = bhi(u.y) * di;
  float a4 = blo(u.z) * di, a5 = bhi(u.z) * di;
  float a6 = blo(u.w) * di, a7 = bhi(u.w) * di;  // self-loop
  int j = off;
  for (; j + 8 <= end; j += 8) {  // 8 gathers in flight
    int ss[8]; float ww[8]; uint4 vv[8];
#pragma unroll
    for (int k = 0; k < 8; ++k) { ss[k] = adj[j + k]; ww[k] = en[j + k]; }
#pragma unroll
    for (int k = 0; k < 8; ++k)
      vv[k] = *(const uint4*)(Hb + (size_t)ss[k] * 128 + l16 * 8);
#pragma unroll
    for (int k = 0; k < 8; ++k) {
      a0 = fmaf(blo(vv[k].x), ww[k], a0); a1 = fmaf(bhi(vv[k].x), ww[k], a1);
      a2 = fmaf(blo(vv[k].y), ww[k], a2); a3 = fmaf(bhi(vv[k].y), ww[k], a3);
      a4 = fmaf(blo(vv[k].z), ww[k], a4); a5 = fmaf(bhi(vv[k].z), ww[k], a5);
      a6 = fmaf(blo(vv[k].w), ww[k], a6); a7 = fmaf(bhi(vv[k].w), ww[k], a7);
    }
  }
  for (; j + 4 <= end; j += 4) {
    int ss[4]; float ww[4]; uint4 vv[4];
#pragma unroll
    for (int k = 0; k < 4; ++k) { ss[k] = adj[j + k]; ww[k] = en[j + k]; }
#pragma unroll
    for (int k = 0; k < 4; ++k)
      vv[k] = *(const uint4*)(Hb + (size_t)ss[k] * 128 + l16 * 8);
#pragma unroll
    for (int k = 0; k < 4; ++k) {
      a0 = fmaf(blo(vv[k].x), ww[k], a0); a1 = fmaf(bhi(vv[k].x), ww[k], a1);
      a2 = fmaf(blo(vv[k].y), ww[k], a2); a3 = fmaf(bhi(vv[k].y), ww[k], a3);
      a4 = fmaf(blo(vv[k].z), ww[k], a4); a5 = fmaf(bhi(vv[k].z), ww[k], a5);
      a6 = fmaf(blo(vv[k].w), ww[k], a6); a7 = fmaf(bhi(vv[k].w), ww[k], a7);
    }
  }
  for (; j < end; ++j) {
    int s = adj[j];
    float w = en[j];
    uint4 v = *(const uint4*)(Hb + (size_t)s * 128 + l16 * 8);
    a0 = fmaf(blo(v.x), w, a0); a1 = fmaf(bhi(v.x), w, a1);
    a2 = fmaf(blo(v.y), w, a2); a3 = fmaf(bhi(v.y), w, a3);
    a4 = fmaf(blo(v.z), w, a4); a5 = fmaf(bhi(v.z), w, a5);
    a6 = fmaf(blo(v.w), w, a6); a7 = fmaf(bhi(v.w), w, a7);
  }
  uint4 pw;
  pw.x = (unsigned int)f2b(a0 * di) | ((unsigned int)f2b(a1 * di) << 16);
  pw.y = (unsigned int)f2b(a2 * di) | ((unsigned int)f2b(a3 * di) << 16);
  pw.z = (unsigned int)f2b(a4 * di) | ((unsigned int)f2b(a5 * di) << 16);
  pw.w = (unsigned int)f2b(a6 * di) | ((unsigned int)f2b(a7 * di) << 16);
  *(uint4*)(out + (size_t)i * 128 + l16 * 8) = pw;
}

// ------------- per-edge exp(leaky(...)) precompute (edge-parallel) -------------
__global__ void gat_ew(const int* __restrict__ adj, const int* __restrict__ eds,
                       const float* __restrict__ als, const float* __restrict__ ald,
                       float2* __restrict__ ew) {
  int j = blockIdx.x * 256 + threadIdx.x;
  if (j >= N_EDGES) return;
  int s = adj[j], d = eds[j];
  float2 a = *(const float2*)(als + 2 * s);
  float2 b = *(const float2*)(ald + 2 * d);
  ew[j] = make_float2(__expf(leaky(a.x + b.x)), __expf(leaky(a.y + b.y)));
}

// -------- GAT aggregation HD=128: 1 node/wave (r10-proven), single pass
// -------- (unnormalized sum + raw-weight denominator), 8/4-wide + scalar tail ----
__global__ __launch_bounds__(256) void gat_pull128(const unsigned short* __restrict__ Hb,
                                                   const int* __restrict__ adj,
                                                   const int* __restrict__ roff,
                                                   const int* __restrict__ deg,
                                                   const float2* __restrict__ ew,
                                                   const float* __restrict__ als,
                                                   const float* __restrict__ ald,
                                                   const float* __restrict__ bias,
                                                   unsigned short* __restrict__ out) {
  int wid = (blockIdx.x * 256 + threadIdx.x) >> 6;
  int lane = threadIdx.x & 63;
  if (wid >= N_NODES) return;
  int i = wid;
  int off = roff[i], end = off + deg[i];
  int head = lane >> 5;
  float p0 = 0.f, p1 = 0.f;  // raw-weight sums (identical across lanes)
  float acc0 = 0.f, acc1 = 0.f, acc2 = 0.f, acc3 = 0.f;  // unnormalized
  int j = off;
  for (; j + 8 <= end; j += 8) {
    int ss[8]; float qq[8]; uint2 vv[8];
#pragma unroll
    for (int k = 0; k < 8; ++k) {
      ss[k] = __builtin_amdgcn_readfirstlane(adj[j + k]);
      float2 w = ew[j + k];
      p0 += w.x; p1 += w.y;
      qq[k] = head ? w.y : w.x;
    }
#pragma unroll
    for (int k = 0; k < 8; ++k)
      vv[k] = *(const uint2*)(Hb + (size_t)ss[k] * 256 + lane * 4);
#pragma unroll
    for (int k = 0; k < 8; ++k) {
      acc0 = fmaf(qq[k], blo(vv[k].x), acc0);
      acc1 = fmaf(qq[k], bhi(vv[k].x), acc1);
      acc2 = fmaf(qq[k], blo(vv[k].y), acc2);
      acc3 = fmaf(qq[k], bhi(vv[k].y), acc3);
    }
  }
  for (; j + 4 <= end; j += 4) {
    int s0 = __builtin_amdgcn_readfirstlane(adj[j]);
    int s1 = __builtin_amdgcn_readfirstlane(adj[j + 1]);
    int s2 = __builtin_amdgcn_readfirstlane(adj[j + 2]);
    int s3 = __builtin_amdgcn_readfirstlane(adj[j + 3]);
    float2 w0 = ew[j], w1 = ew[j + 1], w2 = ew[j + 2], w3 = ew[j + 3];
    p0 += w0.x + w1.x + w2.x + w3.x;
    p1 += w0.y + w1.y + w2.y + w3.y;
    uint2 v0 = *(const uint2*)(Hb + (size_t)s0 * 256 + lane * 4);
    uint2 v1 = *(const uint2*)(Hb + (size_t)s1 * 256 + lane * 4);
    uint2 v2 = *(const uint2*)(Hb + (size_t)s2 * 256 + lane * 4);
    uint2 v3 = *(const uint2*)(Hb + (size_t)s3 * 256 + lane * 4);
    float q0 = head ? w0.y : w0.x;
    float q1 = head ? w1.y : w1.x;
    float q2 = head ? w2.y : w2.x;
    float q3 = head ? w3.y : w3.x;
    acc0 = fmaf(q0, blo(v0.x), acc0); acc1 = fmaf(q0, bhi(v0.x), acc1);
    acc2 = fmaf(q0, blo(v0.y), acc2); acc3 = fmaf(q0, bhi(v0.y), acc3);
    acc0 = fmaf(q1, blo(v1.x), acc0); acc1 = fmaf(q1, bhi(v1.x), acc1);
    acc2 = fmaf(q1, blo(v1.y), acc2); acc3 = fmaf(q1, bhi(v1.y), acc3);
    acc0 = fmaf(q2, blo(v2.x), acc0); acc1 = fmaf(q2, bhi(v2.x), acc1);
    acc2 = fmaf(q2, blo(v2.y), acc2); acc3 = fmaf(q2, bhi(v2.y), acc3);
    acc0 = fmaf(q3, blo(v3.x), acc0); acc1 = fmaf(q3, bhi(v3.x), acc1);
    acc2 = fmaf(q3, blo(v3.y), acc2); acc3 = fmaf(q3, bhi(v3.y), acc3);
  }
  for (; j < end; ++j) {
    int s = __builtin_amdgcn_readfirstlane(adj[j]);
    float2 w = ew[j];
    p0 += w.x; p1 += w.y;
    float q = head ? w.y : w.x;
    uint2 v = *(const uint2*)(Hb + (size_t)s * 256 + lane * 4);
    acc0 = fmaf(q, blo(v.x), acc0);
    acc1 = fmaf(q, bhi(v.x), acc1);
    acc2 = fmaf(q, blo(v.y), acc2);
    acc3 = fmaf(q, bhi(v.y), acc3);
  }
  // self-loop + normalization
  float2 ai = *(const float2*)(als + 2 * i);
  float2 di = *(const float2*)(ald + 2 * i);
  float es0 = __expf(leaky(ai.x + di.x));
  float es1 = __expf(leaky(ai.y + di.y));
  float rsel = head ? (0.5f / (p1 + es1)) : (0.5f / (p0 + es0));  // 0.5 = head mean
  float wself = head ? es1 : es0;
  uint2 u = *(const uint2*)(Hb + (size_t)i * 256 + lane * 4);
  acc0 = (acc0 + wself * blo(u.x)) * rsel;
  acc1 = (acc1 + wself * bhi(u.x)) * rsel;
  acc2 = (acc2 + wself * blo(u.y)) * rsel;
  acc3 = (acc3 + wself * bhi(u.y)) * rsel;
  acc0 += __shfl_xor(acc0, 32, 64);
  acc1 += __shfl_xor(acc1, 32, 64);
  acc2 += __shfl_xor(acc2, 32, 64);
  acc3 += __shfl_xor(acc3, 32, 64);
  if (lane < 32) {
    int c = lane * 4;
    uint2 pw;
    pw.x = (unsigned int)f2b(acc0 + bias[c]) | ((unsigned int)f2b(acc1 + bias[c + 1]) << 16);
    pw.y = (unsigned int)f2b(acc2 + bias[c + 2]) | ((unsigned int)f2b(acc3 + bias[c + 3]) << 16);
    *(uint2*)(out + (size_t)i * 128 + c) = pw;
  }
}

// ---- GAT HD=64 + fused log_softmax: 4 nodes/wave (16 lanes x 16B = 256B row),
// ---- single pass, 8/4-wide unmasked + scalar tail.
// ---- Within a node's 16 lanes: lanes 0-7 = head0 ch[8p..8p+7], 8-15 = head1.
__global__ __launch_bounds__(256) void gat_pull64_lsm(const unsigned short* __restrict__ Hb,
                                                      const int* __restrict__ adj,
                                                      const int* __restrict__ roff,
                                                      const int* __restrict__ deg,
                                                      const float2* __restrict__ ew,
                                                      const float* __restrict__ als,
                                                      const float* __restrict__ ald,
                                                      const float* __restrict__ bias,
                                                      float* __restrict__ out) {
  int wv = (blockIdx.x * 256 + threadIdx.x) >> 6;
  int lane = threadIdx.x & 63;
  int q4 = lane >> 4, l16 = lane & 15;
  int hh = l16 >> 3, p = l16 & 7;  // sub-head and channel-octet within node group
  int i = 4 * wv + q4;
  if (i >= N_NODES) return;
  int off = roff[i], end = off + deg[i];
  int cbase = hh * 64 + 8 * p;  // channel offset within this node's 128-ch row
  float p0 = 0.f, p1 = 0.f;
  float acc0 = 0.f, acc1 = 0.f, acc2 = 0.f, acc3 = 0.f;
  float acc4 = 0.f, acc5 = 0.f, acc6 = 0.f, acc7 = 0.f;
  int j = off;
  for (; j + 8 <= end; j += 8) {
    int ss[8]; float qq[8]; uint4 vv[8];
#pragma unroll
    for (int k = 0; k < 8; ++k) {
      ss[k] = adj[j + k];
      float2 w = ew[j + k];
      p0 += w.x; p1 += w.y;
      qq[k] = hh ? w.y : w.x;
    }
#pragma unroll
    for (int k = 0; k < 8; ++k)
      vv[k] = *(const uint4*)(Hb + (size_t)ss[k] * 128 + cbase);
#pragma unroll
    for (int k = 0; k < 8; ++k) {
      acc0 = fmaf(qq[k], blo(vv[k].x), acc0); acc1 = fmaf(qq[k], bhi(vv[k].x), acc1);
      acc2 = fmaf(qq[k], blo(vv[k].y), acc2); acc3 = fmaf(qq[k], bhi(vv[k].y), acc3);
      acc4 = fmaf(qq[k], blo(vv[k].z), acc4); acc5 = fmaf(qq[k], bhi(vv[k].z), acc5);
      acc6 = fmaf(qq[k], blo(vv[k].w), acc6); acc7 = fmaf(qq[k], bhi(vv[k].w), acc7);
    }
  }
  for (; j + 4 <= end; j += 4) {
    int ss[4]; float qq[4]; uint4 vv[4];
#pragma unroll
    for (int k = 0; k < 4; ++k) {
      ss[k] = adj[j + k];
      float2 w = ew[j + k];
      p0 += w.x; p1 += w.y;
      qq[k] = hh ? w.y : w.x;
    }
#pragma unroll
    for (int k = 0; k < 4; ++k)
      vv[k] = *(const uint4*)(Hb + (size_t)ss[k] * 128 + cbase);
#pragma unroll
    for (int k = 0; k < 4; ++k) {
      acc0 = fmaf(qq[k], blo(vv[k].x), acc0); acc1 = fmaf(qq[k], bhi(vv[k].x), acc1);
      acc2 = fmaf(qq[k], blo(vv[k].y), acc2); acc3 = fmaf(qq[k], bhi(vv[k].y), acc3);
      acc4 = fmaf(qq[k], blo(vv[k].z), acc4); acc5 = fmaf(qq[k], bhi(vv[k].z), acc5);
      acc6 = fmaf(qq[k], blo(vv[k].w), acc6); acc7 = fmaf(qq[k], bhi(vv[k].w), acc7);
    }
  }
  for (; j < end; ++j) {
    int s = adj[j];
    float2 w = ew[j];
    p0 += w.x; p1 += w.y;
    float q = hh ? w.y : w.x;
    uint4 v = *(const uint4*)(Hb + (size_t)s * 128 + cbase);
    acc0 = fmaf(q, blo(v.x), acc0); acc1 = fmaf(q, bhi(v.x), acc1);
    acc2 = fmaf(q, blo(v.y), acc2); acc3 = fmaf(q, bhi(v.y), acc3);
    acc4 = fmaf(q, blo(v.z), acc4); acc5 = fmaf(q, bhi(v.z), acc5);
    acc6 = fmaf(q, blo(v.w), acc6); acc7 = fmaf(q, bhi(v.w), acc7);
  }
  // self-loop + normalization
  float2 ai = *(const float2*)(als + 2 * i);
  float2 dd = *(const float2*)(ald + 2 * i);
  float es0 = __expf(leaky(ai.x + dd.x));
  float es1 = __expf(leaky(ai.y + dd.y));
  float rsel = hh ? (0.5f / (p1 + es1)) : (0.5f / (p0 + es0));
  float wself = hh ? es1 : es0;
  uint4 u = *(const uint4*)(Hb + (size_t)i * 128 + cbase);
  acc0 = (acc0 + wself * blo(u.x)) * rsel; acc1 = (acc1 + wself * bhi(u.x)) * rsel;
  acc2 = (acc2 + wself * blo(u.y)) * rsel; acc3 = (acc3 + wself * bhi(u.y)) * rsel;
  acc4 = (acc4 + wself * blo(u.z)) * rsel; acc5 = (acc5 + wself * bhi(u.z)) * rsel;
  acc6 = (acc6 + wself * blo(u.w)) * rsel; acc7 = (acc7 + wself * bhi(u.w)) * rsel;
  // head combine: lane p (head0 ch 8p..) + lane 8+p (head1 ch 8p..)
  acc0 += __shfl_xor(acc0, 8, 64); acc1 += __shfl_xor(acc1, 8, 64);
  acc2 += __shfl_xor(acc2, 8, 64); acc3 += __shfl_xor(acc3, 8, 64);
  acc4 += __shfl_xor(acc4, 8, 64); acc5 += __shfl_xor(acc5, 8, 64);
  acc6 += __shfl_xor(acc6, 8, 64); acc7 += __shfl_xor(acc7, 8, 64);
  float4 b0 = *(const float4*)(bias + 8 * p);
  float4 b1 = *(const float4*)(bias + 8 * p + 4);
  float v0 = acc0 + b0.x, v1 = acc1 + b0.y, v2 = acc2 + b0.z, v3 = acc3 + b0.w;
  float v4 = acc4 + b1.x, v5 = acc5 + b1.y, v6 = acc6 + b1.z, v7 = acc7 + b1.w;
  // log_softmax over 64 ch = 8 lanes x 8 vals (lanes 8-15 hold identical sums)
  float mv = fmaxf(fmaxf(fmaxf(v0, v1), fmaxf(v2, v3)),
                   fmaxf(fmaxf(v4, v5), fmaxf(v6, v7)));
#pragma unroll
  for (int mm = 4; mm > 0; mm >>= 1) mv = fmaxf(mv, __shfl_xor(mv, mm, 64));
  float sv = __expf(v0 - mv) + __expf(v1 - mv) + __expf(v2 - mv) + __expf(v3 - mv) +
             __expf(v4 - mv) + __expf(v5 - mv) + __expf(v6 - mv) + __expf(v7 - mv);
#pragma unroll
  for (int mm = 4; mm > 0; mm >>= 1) sv += __shfl_xor(sv, mm, 64);
  float ls = mv + __logf(sv);
  if (hh == 0) {
    *(float4*)(out + (size_t)i * 64 + 8 * p) =
        make_float4(v0 - ls, v1 - ls, v2 - ls, v3 - ls);
    *(float4*)(out + (size_t)i * 64 + 8 * p + 4) =
        make_float4(v4 - ls, v5 - ls, v6 - ls, v7 - ls);
  }
}

extern "C" void kernel_launch(void* const* d_in, const int* in_sizes, int n_in, void* d_out,
                              int out_size, void* d_ws, size_t ws_size, hipStream_t stream) {
  const float* x      = (const float*)d_in[0];
  const int* eidx     = (const int*)d_in[1];
  const float* W_gcn1 = (const float*)d_in[2];
  const float* b_gcn1 = (const float*)d_in[3];
  const float* bn1_g  = (const float*)d_in[4];
  const float* bn1_b  = (const float*)d_in[5];
  const float* bn1_m  = (const float*)d_in[6];
  const float* bn1_v  = (const float*)d_in[7];
  const float* W_gat1 = (const float*)d_in[8];
  const float* a_src1 = (const float*)d_in[9];
  const float* a_dst1 = (const float*)d_in[10];
  const float* b_gat1 = (const float*)d_in[11];
  const float* W_gcn2 = (const float*)d_in[12];
  const float* b_gcn2 = (const float*)d_in[13];
  const float* bn2_g  = (const float*)d_in[14];
  const float* bn2_b  = (const float*)d_in[15];
  const float* bn2_m  = (const float*)d_in[16];
  const float* bn2_v  = (const float*)d_in[17];
  const float* W_gat2 = (const float*)d_in[18];
  const float* a_src2 = (const float*)d_in[19];
  const float* a_dst2 = (const float*)d_in[20];
  const float* b_gat2 = (const float*)d_in[21];

  char* ws = (char*)d_ws;
  size_t o = 0;
  auto take = [&](size_t bytes) {
    char* p = ws + o;
    o = (o + bytes + 255) & ~(size_t)255;
    return p;
  };
  int* srcs    = (int*)take((size_t)N_EDGES * 4);
  int* dstsb   = (int*)take((size_t)N_EDGES * 4);
  int* deg     = (int*)take((size_t)(N_NODES + 64) * 4);  // +1 int (gbase), memset together
  int* gbase   = deg + N_NODES;
  int* roff    = (int*)take((size_t)N_NODES * 4);
  int* cursor  = (int*)take((size_t)N_NODES * 4);
  int* adj     = (int*)take((size_t)N_EDGES * 4);
  int* eds     = (int*)take((size_t)N_EDGES * 4);
  float* en    = (float*)take((size_t)N_EDGES * 4);
  float2* ew   = (float2*)take((size_t)N_EDGES * 8);
  float* dinv  = (float*)take((size_t)N_NODES * 4);
  float* als   = (float*)take((size_t)2 * N_NODES * 4);
  float* ald   = (float*)take((size_t)2 * N_NODES * 4);
  float* sc1   = (float*)take(128 * 4);
  float* sh1   = (float*)take(128 * 4);
  float* sc2   = (float*)take(128 * 4);
  float* sh2   = (float*)take(128 * 4);
  unsigned short* Wt1  = (unsigned short*)take((size_t)128 * 128 * 2);
  unsigned short* WtG1 = (unsigned short*)take((size_t)256 * 128 * 2);
  unsigned short* Wt2  = (unsigned short*)take((size_t)128 * 128 * 2);
  unsigned short* WtG2 = (unsigned short*)take((size_t)128 * 128 * 2);
  unsigned short* Hb   = (unsigned short*)take((size_t)N_NODES * 256 * 2);
  unsigned short* Pb   = (unsigned short*)take((size_t)N_NODES * 128 * 2);
  (void)ws_size; (void)in_sizes; (void)n_in; (void)out_size;

  int eb = (N_EDGES + 255) / 256;
  int nb = (N_NODES + 255) / 256;
  int wb = (N_NODES + 3) / 4;              // wave per node (gat_pull128)
  int qb = ((N_NODES + 3) / 4 + 3) / 4;    // wave per 4 nodes (gcn_pull, lsm)
  int gb = (N_NODES + 63) / 64;            // MFMA-GEMM blocks

  // CSR build + prep (k_prep fused into k_convert; 3 scan kernels -> k_offsets)
  hipMemsetAsync(deg, 0, (size_t)(N_NODES + 1) * 4, stream);
  k_convert<<<eb, 256, 0, stream>>>(eidx, srcs, dstsb, deg, W_gcn1, W_gat1, W_gcn2, W_gat2,
                                    Wt1, WtG1, Wt2, WtG2, b_gcn1, bn1_g, bn1_b, bn1_m, bn1_v,
                                    b_gcn2, bn2_g, bn2_b, bn2_m, bn2_v, sc1, sh1, sc2, sh2);
  k_offsets<<<nb, 256, 0, stream>>>(deg, gbase, roff, cursor, dinv);
  k_fill<<<eb, 256, 0, stream>>>(srcs, dstsb, cursor, adj, eds, dinv, en);

  // Layer pipeline (all intermediates bf16; gat_al fused into GEMM epilogues)
  gemm_mfma<128, 0><<<gb, 256, 0, stream>>>(x, Wt1, Hb, (const float*)nullptr,
                                            (const float*)nullptr, 0, nullptr, nullptr,
                                            nullptr, nullptr);
  gcn_pull<<<qb, 256, 0, stream>>>(Hb, adj, roff, deg, en, dinv, Pb);
  gemm_mfma<256, 1><<<gb, 256, 0, stream>>>(Pb, WtG1, Hb, sc1, sh1, 2, a_src1, a_dst1,
                                            als, ald);
  gat_ew<<<eb, 256, 0, stream>>>(adj, eds, als, ald, ew);
  gat_pull128<<<wb, 256, 0, stream>>>(Hb, adj, roff, deg, ew, als, ald, b_gat1, Pb);
  gemm_mfma<128, 0><<<gb, 256, 0, stream>>>(Pb, Wt2, Hb, (const float*)nullptr,
                                            (const float*)nullptr, 1, nullptr, nullptr,
                                            nullptr, nullptr);
  gcn_pull<<<qb, 256, 0, stream>>>(Hb, adj, roff, deg, en, dinv, Pb);
  gemm_mfma<128, 1><<<gb, 256, 0, stream>>>(Pb, WtG2, Hb, sc2, sh2, 2, a_src2, a_dst2,
                                            als, ald);
  gat_ew<<<eb, 256, 0, stream>>>(adj, eds, als, ald, ew);
  gat_pull64_lsm<<<qb, 256, 0, stream>>>(Hb, adj, roff, deg, ew, als, ald, b_gat2,
                                         (float*)d_out);
}

// Round 14
// 430.291 us; speedup vs baseline: 1.0336x; 1.0218x over previous
//
#include <hip/hip_runtime.h>
#include <hip/hip_bf16.h>

#define N_NODES 50000
#define N_EDGES 600000

typedef short bf16x8 __attribute__((ext_vector_type(8)));
typedef float f32x4 __attribute__((ext_vector_type(4)));

__device__ __forceinline__ float leaky(float e) { return e > 0.f ? e : 0.2f * e; }
__device__ __forceinline__ unsigned short f2b(float f) {
  __hip_bfloat16 h = __float2bfloat16(f);
  return *reinterpret_cast<unsigned short*>(&h);
}
__device__ __forceinline__ float blo(unsigned int u) { return __uint_as_float(u << 16); }
__device__ __forceinline__ float bhi(unsigned int u) { return __uint_as_float(u & 0xffff0000u); }
__device__ __forceinline__ float pick4(float a0, float a1, float a2, float a3, int r) {
  float x = (r & 1) ? a1 : a0;
  float y = (r & 1) ? a3 : a2;
  return (r & 2) ? y : x;
}

// ------- edge convert (detect int64 vs int32) + degree count + weight prep -------
__global__ void k_convert(const int* __restrict__ e, int* __restrict__ src32,
                          int* __restrict__ dst32, int* __restrict__ deg,
                          const float* __restrict__ W1, const float* __restrict__ WG1,
                          const float* __restrict__ W2, const float* __restrict__ WG2,
                          unsigned short* __restrict__ Wt1, unsigned short* __restrict__ WtG1,
                          unsigned short* __restrict__ Wt2, unsigned short* __restrict__ WtG2,
                          const float* b1, const float* g1, const float* be1, const float* m1,
                          const float* v1, const float* b2, const float* g2, const float* be2,
                          const float* m2, const float* v2, float* sc1, float* sh1,
                          float* sc2, float* sh2) {
  __shared__ int sflag;
  int tid = threadIdx.x;
  if (tid < 64) {  // wave 0: sample odd int32 words; all-zero => int64 input
    int idx = 1 + 2 * tid * 4096;
    int v = e[idx];
    unsigned long long nz = __ballot(v != 0);
    if (tid == 0) sflag = (nz == 0ULL) ? 1 : 0;
  }
  __syncthreads();
  int f = sflag;
  int i = blockIdx.x * 256 + tid;
  if (i < N_EDGES) {
    int s, d;
    if (f) { s = e[2 * i]; d = e[2 * (N_EDGES + i)]; }
    else   { s = e[i];     d = e[N_EDGES + i]; }
    src32[i] = s;
    dst32[i] = d;
    atomicAdd(&deg[d], 1);
  }
  // fused prep (independent outputs, same index space)
  if (i < 16384) {
    int k = i >> 7, c = i & 127;
    Wt1[c * 128 + k] = f2b(W1[i]);
  } else if (i < 49152) {
    int l = i - 16384;
    int k = l >> 8, c = l & 255;
    WtG1[c * 128 + k] = f2b(WG1[l]);
  } else if (i < 65536) {
    int l = i - 49152;
    int k = l >> 7, c = l & 127;
    Wt2[c * 128 + k] = f2b(W2[l]);
  } else if (i < 81920) {
    int l = i - 65536;
    int k = l >> 7, c = l & 127;
    WtG2[c * 128 + k] = f2b(WG2[l]);
  } else if (i < 82048) {
    int c = i - 81920;
    float s = g1[c] * rsqrtf(v1[c] + 1e-5f);
    sc1[c] = s;
    sh1[c] = (b1[c] - m1[c]) * s + be1[c];
  } else if (i < 82176) {
    int c = i - 82048;
    float s = g2[c] * rsqrtf(v2[c] + 1e-5f);
    sc2[c] = s;
    sh2[c] = (b2[c] - m2[c]) * s + be2[c];
  }
}

// ---- CSR offsets in one kernel: block-local scan + atomic block base.
// roff is NOT globally monotone — consumers use end = roff[i] + deg[i].
__global__ void k_offsets(const int* __restrict__ deg, int* __restrict__ gbase,
                          int* __restrict__ roff, int* __restrict__ cursor,
                          float* __restrict__ dinv) {
  __shared__ int s[256];
  __shared__ int base;
  int t = threadIdx.x;
  int i = blockIdx.x * 256 + t;
  int v = (i < N_NODES) ? deg[i] : 0;
  s[t] = v;
  __syncthreads();
  for (int o = 1; o < 256; o <<= 1) {
    int x = (t >= o) ? s[t - o] : 0;
    __syncthreads();
    s[t] += x;
    __syncthreads();
  }
  if (t == 255) base = atomicAdd(gbase, s[255]);
  __syncthreads();
  int off = base + s[t] - v;
  if (i < N_NODES) {
    roff[i] = off;
    cursor[i] = off;
    dinv[i] = rsqrtf((float)v + 1.f);
  }
}
// fill CSR slots: adj=src, en=dinv[src]
__global__ void k_fill(const int* __restrict__ src, const int* __restrict__ dst,
                       int* __restrict__ cursor, int* __restrict__ adj,
                       const float* __restrict__ dinv, float* __restrict__ en) {
  int e = blockIdx.x * 256 + threadIdx.x;
  if (e < N_EDGES) {
    int s = src[e], d = dst[e];
    int pos = atomicAdd(&cursor[d], 1);
    adj[pos] = s;
    en[pos] = dinv[s];
  }
}

// 4-channel loader: fp32 or packed-bf16 source
__device__ __forceinline__ float4 ld4(const float* X, size_t idx) {
  return *(const float4*)(X + idx);
}
__device__ __forceinline__ float4 ld4(const unsigned short* X, size_t idx) {
  uint2 r = *(const uint2*)(X + idx);
  return make_float4(blo(r.x), bhi(r.x), blo(r.y), bhi(r.y));
}

// ---------------- MFMA GEMM: Hb[n,C] = bf16( T(X[n,128]) @ W[128,C] ) ----------
// T: 0=identity, 1=relu, 2=relu(affine). 64 rows/block, wave = 16 rows x C cols.
// AL=1: emit GAT logits als/ald straight from the fp32 accumulator registers.
template <int C, int AL, typename TX>
__global__ __launch_bounds__(256) void gemm_mfma(const TX* __restrict__ X,
                                                 const unsigned short* __restrict__ Wt,
                                                 unsigned short* __restrict__ Hb,
                                                 const float* __restrict__ scale,
                                                 const float* __restrict__ shift, int mode,
                                                 const float* __restrict__ a_src,
                                                 const float* __restrict__ a_dst,
                                                 float* __restrict__ als,
                                                 float* __restrict__ ald) {
  __shared__ __align__(16) short smem[(C == 256) ? 16384 : 8704];
  int tid = threadIdx.x;
  int row0 = blockIdx.x * 64;
  for (int i = tid; i < 2048; i += 256) {
    int r = i >> 5;
    int k4 = (i & 31) * 4;
    int row = row0 + r;
    float4 v = make_float4(0.f, 0.f, 0.f, 0.f);
    if (row < N_NODES) v = ld4(X, (size_t)row * 128 + k4);
    if (mode == 2) {
      v.x = v.x * scale[k4] + shift[k4];
      v.y = v.y * scale[k4 + 1] + shift[k4 + 1];
      v.z = v.z * scale[k4 + 2] + shift[k4 + 2];
      v.w = v.w * scale[k4 + 3] + shift[k4 + 3];
    }
    if (mode >= 1) {
      v.x = fmaxf(v.x, 0.f); v.y = fmaxf(v.y, 0.f);
      v.z = fmaxf(v.z, 0.f); v.w = fmaxf(v.w, 0.f);
    }
    uint2 p;
    p.x = (unsigned int)f2b(v.x) | ((unsigned int)f2b(v.y) << 16);
    p.y = (unsigned int)f2b(v.z) | ((unsigned int)f2b(v.w) << 16);
    *(uint2*)&smem[r * 136 + k4] = p;
  }
  __syncthreads();
  int wave = tid >> 6, lane = tid & 63;
  int m = lane & 15, quad = lane >> 4;
  int rl0 = wave * 16;
  bf16x8 a[4];
#pragma unroll
  for (int kk = 0; kk < 4; ++kk)
    a[kk] = *(const bf16x8*)&smem[(rl0 + m) * 136 + kk * 32 + quad * 8];
  f32x4 acc[C / 16];
#pragma unroll
  for (int ct = 0; ct < C / 16; ++ct) acc[ct] = (f32x4){0.f, 0.f, 0.f, 0.f};
#pragma unroll
  for (int ct = 0; ct < C / 16; ++ct) {
    const unsigned short* wp = Wt + (size_t)(ct * 16 + m) * 128 + quad * 8;
#pragma unroll
    for (int kk = 0; kk < 4; ++kk) {
      bf16x8 b = *(const bf16x8*)(wp + kk * 32);
      acc[ct] = __builtin_amdgcn_mfma_f32_16x16x32_bf16(a[kk], b, acc[ct], 0, 0, 0);
    }
  }
  if (AL) {
    float s0[4] = {0.f, 0.f, 0.f, 0.f}, s1[4] = {0.f, 0.f, 0.f, 0.f};
    float d0[4] = {0.f, 0.f, 0.f, 0.f}, d1[4] = {0.f, 0.f, 0.f, 0.f};
#pragma unroll
    for (int ct = 0; ct < C / 16; ++ct) {
      float as = a_src[ct * 16 + m];
      float ad = a_dst[ct * 16 + m];
#pragma unroll
      for (int reg = 0; reg < 4; ++reg) {
        float v = acc[ct][reg];
        if (ct < C / 32) {
          s0[reg] = fmaf(v, as, s0[reg]);
          d0[reg] = fmaf(v, ad, d0[reg]);
        } else {
          s1[reg] = fmaf(v, as, s1[reg]);
          d1[reg] = fmaf(v, ad, d1[reg]);
        }
      }
    }
#pragma unroll
    for (int mask = 1; mask <= 8; mask <<= 1) {
#pragma unroll
      for (int reg = 0; reg < 4; ++reg) {
        s0[reg] += __shfl_xor(s0[reg], mask, 64);
        s1[reg] += __shfl_xor(s1[reg], mask, 64);
        d0[reg] += __shfl_xor(d0[reg], mask, 64);
        d1[reg] += __shfl_xor(d1[reg], mask, 64);
      }
    }
    int reg = m & 3, hsel = (m >> 2) & 1, dsel = m >> 3;
    float sv = hsel ? pick4(s1[0], s1[1], s1[2], s1[3], reg)
                    : pick4(s0[0], s0[1], s0[2], s0[3], reg);
    float dv = hsel ? pick4(d1[0], d1[1], d1[2], d1[3], reg)
                    : pick4(d0[0], d0[1], d0[2], d0[3], reg);
    int row = row0 + rl0 + quad * 4 + reg;
    if (row < N_NODES) {
      float* dst = dsel ? ald : als;
      dst[2 * row + hsel] = dsel ? dv : sv;
    }
  }
  __syncthreads();
#pragma unroll
  for (int ct = 0; ct < C / 16; ++ct) {
#pragma unroll
    for (int reg = 0; reg < 4; ++reg) {
      int rl = rl0 + quad * 4 + reg;
      smem[rl * C + ct * 16 + m] = (short)f2b(acc[ct][reg]);
    }
  }
  __syncthreads();
  for (int i = tid; i < 8 * C; i += 256) {
    int row = row0 + (i * 8) / C;
    if (row < N_NODES)
      *(uint4*)((char*)Hb + (size_t)row0 * C * 2 + (size_t)i * 16) =
          *(uint4*)((char*)smem + (size_t)i * 16);
  }
}

// ---- GCN aggregation: 4 nodes per wave (16 lanes x 16B = 256B node row),
// ---- per-quarter loop: 8/4-wide unmasked + scalar tail, bf16 I/O ----
__global__ __launch_bounds__(256) void gcn_pull(const unsigned short* __restrict__ Hb,
                                                const int* __restrict__ adj,
                                                const int* __restrict__ roff,
                                                const int* __restrict__ deg,
                                                const float* __restrict__ en,
                                                const float* __restrict__ dinv,
                                                unsigned short* __restrict__ out) {
  int wv = (blockIdx.x * 256 + threadIdx.x) >> 6;
  int lane = threadIdx.x & 63;
  int q4 = lane >> 4, l16 = lane & 15;
  int i = 4 * wv + q4;
  if (i >= N_NODES) return;  // exec-masked quarter-exit
  int off = roff[i], end = off + deg[i];
  float di = dinv[i];
  uint4 u = *(const uint4*)(Hb + (size_t)i * 128 + l16 * 8);
  float a0 = blo(u.x) * di, a1 = bhi(u.x) * di;
  float a2 = blo(u.y) * di, a3 = bhi(u.y) * di;
  float a4 = blo(u.z) * di, a5 = bhi(u.z) * di;
  float a6 = blo(u.w) * di, a7 = bhi(u.w) * di;  // self-loop
  int j = off;
  for (; j + 8 <= end; j += 8) {  // 8 gathers in flight
    int ss[8]; float ww[8]; uint4 vv[8];
#pragma unroll
    for (int k = 0; k < 8; ++k) { ss[k] = adj[j + k]; ww[k] = en[j + k]; }
#pragma unroll
    for (int k = 0; k < 8; ++k)
      vv[k] = *(const uint4*)(Hb + (size_t)ss[k] * 128 + l16 * 8);
#pragma unroll
    for (int k = 0; k < 8; ++k) {
      a0 = fmaf(blo(vv[k].x), ww[k], a0); a1 = fmaf(bhi(vv[k].x), ww[k], a1);
      a2 = fmaf(blo(vv[k].y), ww[k], a2); a3 = fmaf(bhi(vv[k].y), ww[k], a3);
      a4 = fmaf(blo(vv[k].z), ww[k], a4); a5 = fmaf(bhi(vv[k].z), ww[k], a5);
      a6 = fmaf(blo(vv[k].w), ww[k], a6); a7 = fmaf(bhi(vv[k].w), ww[k], a7);
    }
  }
  for (; j + 4 <= end; j += 4) {
    int ss[4]; float ww[4]; uint4 vv[4];
#pragma unroll
    for (int k = 0; k < 4; ++k) { ss[k] = adj[j + k]; ww[k] = en[j + k]; }
#pragma unroll
    for (int k = 0; k < 4; ++k)
      vv[k] = *(const uint4*)(Hb + (size_t)ss[k] * 128 + l16 * 8);
#pragma unroll
    for (int k = 0; k < 4; ++k) {
      a0 = fmaf(blo(vv[k].x), ww[k], a0); a1 = fmaf(bhi(vv[k].x), ww[k], a1);
      a2 = fmaf(blo(vv[k].y), ww[k], a2); a3 = fmaf(bhi(vv[k].y), ww[k], a3);
      a4 = fmaf(blo(vv[k].z), ww[k], a4); a5 = fmaf(bhi(vv[k].z), ww[k], a5);
      a6 = fmaf(blo(vv[k].w), ww[k], a6); a7 = fmaf(bhi(vv[k].w), ww[k], a7);
    }
  }
  for (; j < end; ++j) {
    int s = adj[j];
    float w = en[j];
    uint4 v = *(const uint4*)(Hb + (size_t)s * 128 + l16 * 8);
    a0 = fmaf(blo(v.x), w, a0); a1 = fmaf(bhi(v.x), w, a1);
    a2 = fmaf(blo(v.y), w, a2); a3 = fmaf(bhi(v.y), w, a3);
    a4 = fmaf(blo(v.z), w, a4); a5 = fmaf(bhi(v.z), w, a5);
    a6 = fmaf(blo(v.w), w, a6); a7 = fmaf(bhi(v.w), w, a7);
  }
  uint4 pw;
  pw.x = (unsigned int)f2b(a0 * di) | ((unsigned int)f2b(a1 * di) << 16);
  pw.y = (unsigned int)f2b(a2 * di) | ((unsigned int)f2b(a3 * di) << 16);
  pw.z = (unsigned int)f2b(a4 * di) | ((unsigned int)f2b(a5 * di) << 16);
  pw.w = (unsigned int)f2b(a6 * di) | ((unsigned int)f2b(a7 * di) << 16);
  *(uint4*)(out + (size_t)i * 128 + l16 * 8) = pw;
}

// -------- GAT aggregation HD=128: 1 node/wave, single pass, inline edge exps
// -------- (weights from als[s]+ald[i] — no ew stage), 8/4-wide + scalar tail ----
__global__ __launch_bounds__(256) void gat_pull128(const unsigned short* __restrict__ Hb,
                                                   const int* __restrict__ adj,
                                                   const int* __restrict__ roff,
                                                   const int* __restrict__ deg,
                                                   const float* __restrict__ als,
                                                   const float* __restrict__ ald,
                                                   const float* __restrict__ bias,
                                                   unsigned short* __restrict__ out) {
  int wid = (blockIdx.x * 256 + threadIdx.x) >> 6;
  int lane = threadIdx.x & 63;
  if (wid >= N_NODES) return;
  int i = wid;
  int off = roff[i], end = off + deg[i];
  int head = lane >> 5;
  float2 di = *(const float2*)(ald + 2 * i);
  float p0 = 0.f, p1 = 0.f;  // raw-weight sums (identical across lanes)
  float acc0 = 0.f, acc1 = 0.f, acc2 = 0.f, acc3 = 0.f;  // unnormalized
  int j = off;
  for (; j + 8 <= end; j += 8) {
    int ss[8]; float qq[8]; uint2 vv[8];
#pragma unroll
    for (int k = 0; k < 8; ++k)
      ss[k] = __builtin_amdgcn_readfirstlane(adj[j + k]);
#pragma unroll
    for (int k = 0; k < 8; ++k)  // gathers first: overlap exps with latency
      vv[k] = *(const uint2*)(Hb + (size_t)ss[k] * 256 + lane * 4);
#pragma unroll
    for (int k = 0; k < 8; ++k) {
      float2 a = *(const float2*)(als + 2 * ss[k]);
      float e0 = __expf(leaky(a.x + di.x));
      float e1 = __expf(leaky(a.y + di.y));
      p0 += e0; p1 += e1;
      qq[k] = head ? e1 : e0;
    }
#pragma unroll
    for (int k = 0; k < 8; ++k) {
      acc0 = fmaf(qq[k], blo(vv[k].x), acc0);
      acc1 = fmaf(qq[k], bhi(vv[k].x), acc1);
      acc2 = fmaf(qq[k], blo(vv[k].y), acc2);
      acc3 = fmaf(qq[k], bhi(vv[k].y), acc3);
    }
  }
  for (; j + 4 <= end; j += 4) {
    int ss[4]; float qq[4]; uint2 vv[4];
#pragma unroll
    for (int k = 0; k < 4; ++k)
      ss[k] = __builtin_amdgcn_readfirstlane(adj[j + k]);
#pragma unroll
    for (int k = 0; k < 4; ++k)
      vv[k] = *(const uint2*)(Hb + (size_t)ss[k] * 256 + lane * 4);
#pragma unroll
    for (int k = 0; k < 4; ++k) {
      float2 a = *(const float2*)(als + 2 * ss[k]);
      float e0 = __expf(leaky(a.x + di.x));
      float e1 = __expf(leaky(a.y + di.y));
      p0 += e0; p1 += e1;
      qq[k] = head ? e1 : e0;
    }
#pragma unroll
    for (int k = 0; k < 4; ++k) {
      acc0 = fmaf(qq[k], blo(vv[k].x), acc0);
      acc1 = fmaf(qq[k], bhi(vv[k].x), acc1);
      acc2 = fmaf(qq[k], blo(vv[k].y), acc2);
      acc3 = fmaf(qq[k], bhi(vv[k].y), acc3);
    }
  }
  for (; j < end; ++j) {
    int s = __builtin_amdgcn_readfirstlane(adj[j]);
    float2 a = *(const float2*)(als + 2 * s);
    float e0 = __expf(leaky(a.x + di.x));
    float e1 = __expf(leaky(a.y + di.y));
    p0 += e0; p1 += e1;
    float q = head ? e1 : e0;
    uint2 v = *(const uint2*)(Hb + (size_t)s * 256 + lane * 4);
    acc0 = fmaf(q, blo(v.x), acc0);
    acc1 = fmaf(q, bhi(v.x), acc1);
    acc2 = fmaf(q, blo(v.y), acc2);
    acc3 = fmaf(q, bhi(v.y), acc3);
  }
  // self-loop + normalization
  float2 ai = *(const float2*)(als + 2 * i);
  float es0 = __expf(leaky(ai.x + di.x));
  float es1 = __expf(leaky(ai.y + di.y));
  float rsel = head ? (0.5f / (p1 + es1)) : (0.5f / (p0 + es0));  // 0.5 = head mean
  float wself = head ? es1 : es0;
  uint2 u = *(const uint2*)(Hb + (size_t)i * 256 + lane * 4);
  acc0 = (acc0 + wself * blo(u.x)) * rsel;
  acc1 = (acc1 + wself * bhi(u.x)) * rsel;
  acc2 = (acc2 + wself * blo(u.y)) * rsel;
  acc3 = (acc3 + wself * bhi(u.y)) * rsel;
  acc0 += __shfl_xor(acc0, 32, 64);
  acc1 += __shfl_xor(acc1, 32, 64);
  acc2 += __shfl_xor(acc2, 32, 64);
  acc3 += __shfl_xor(acc3, 32, 64);
  if (lane < 32) {
    int c = lane * 4;
    uint2 pw;
    pw.x = (unsigned int)f2b(acc0 + bias[c]) | ((unsigned int)f2b(acc1 + bias[c + 1]) << 16);
    pw.y = (unsigned int)f2b(acc2 + bias[c + 2]) | ((unsigned int)f2b(acc3 + bias[c + 3]) << 16);
    *(uint2*)(out + (size_t)i * 128 + c) = pw;
  }
}

// ---- GAT HD=64 + fused log_softmax: 4 nodes/wave (16 lanes x 16B = 256B row),
// ---- single pass, inline edge exps, 8/4-wide unmasked + scalar tail.
// ---- Within a node's 16 lanes: lanes 0-7 = head0 ch[8p..8p+7], 8-15 = head1.
__global__ __launch_bounds__(256) void gat_pull64_lsm(const unsigned short* __restrict__ Hb,
                                                      const int* __restrict__ adj,
                                                      const int* __restrict__ roff,
                                                      const int* __restrict__ deg,
                                                      const float* __restrict__ als,
                                                      const float* __restrict__ ald,
                                                      const float* __restrict__ bias,
                                                      float* __restrict__ out) {
  int wv = (blockIdx.x * 256 + threadIdx.x) >> 6;
  int lane = threadIdx.x & 63;
  int q4 = lane >> 4, l16 = lane & 15;
  int hh = l16 >> 3, p = l16 & 7;  // sub-head and channel-octet within node group
  int i = 4 * wv + q4;
  if (i >= N_NODES) return;
  int off = roff[i], end = off + deg[i];
  int cbase = hh * 64 + 8 * p;  // channel offset within this node's 128-ch row
  float2 dd = *(const float2*)(ald + 2 * i);
  float p0 = 0.f, p1 = 0.f;
  float acc0 = 0.f, acc1 = 0.f, acc2 = 0.f, acc3 = 0.f;
  float acc4 = 0.f, acc5 = 0.f, acc6 = 0.f, acc7 = 0.f;
  int j = off;
  for (; j + 8 <= end; j += 8) {
    int ss[8]; float qq[8]; uint4 vv[8];
#pragma unroll
    for (int k = 0; k < 8; ++k) ss[k] = adj[j + k];
#pragma unroll
    for (int k = 0; k < 8; ++k)
      vv[k] = *(const uint4*)(Hb + (size_t)ss[k] * 128 + cbase);
#pragma unroll
    for (int k = 0; k < 8; ++k) {
      float2 a = *(const float2*)(als + 2 * ss[k]);
      float e0 = __expf(leaky(a.x + dd.x));
      float e1 = __expf(leaky(a.y + dd.y));
      p0 += e0; p1 += e1;
      qq[k] = hh ? e1 : e0;
    }
#pragma unroll
    for (int k = 0; k < 8; ++k) {
      acc0 = fmaf(qq[k], blo(vv[k].x), acc0); acc1 = fmaf(qq[k], bhi(vv[k].x), acc1);
      acc2 = fmaf(qq[k], blo(vv[k].y), acc2); acc3 = fmaf(qq[k], bhi(vv[k].y), acc3);
      acc4 = fmaf(qq[k], blo(vv[k].z), acc4); acc5 = fmaf(qq[k], bhi(vv[k].z), acc5);
      acc6 = fmaf(qq[k], blo(vv[k].w), acc6); acc7 = fmaf(qq[k], bhi(vv[k].w), acc7);
    }
  }
  for (; j + 4 <= end; j += 4) {
    int ss[4]; float qq[4]; uint4 vv[4];
#pragma unroll
    for (int k = 0; k < 4; ++k) ss[k] = adj[j + k];
#pragma unroll
    for (int k = 0; k < 4; ++k)
      vv[k] = *(const uint4*)(Hb + (size_t)ss[k] * 128 + cbase);
#pragma unroll
    for (int k = 0; k < 4; ++k) {
      float2 a = *(const float2*)(als + 2 * ss[k]);
      float e0 = __expf(leaky(a.x + dd.x));
      float e1 = __expf(leaky(a.y + dd.y));
      p0 += e0; p1 += e1;
      qq[k] = hh ? e1 : e0;
    }
#pragma unroll
    for (int k = 0; k < 4; ++k) {
      acc0 = fmaf(qq[k], blo(vv[k].x), acc0); acc1 = fmaf(qq[k], bhi(vv[k].x), acc1);
      acc2 = fmaf(qq[k], blo(vv[k].y), acc2); acc3 = fmaf(qq[k], bhi(vv[k].y), acc3);
      acc4 = fmaf(qq[k], blo(vv[k].z), acc4); acc5 = fmaf(qq[k], bhi(vv[k].z), acc5);
      acc6 = fmaf(qq[k], blo(vv[k].w), acc6); acc7 = fmaf(qq[k], bhi(vv[k].w), acc7);
    }
  }
  for (; j < end; ++j) {
    int s = adj[j];
    float2 a = *(const float2*)(als + 2 * s);
    float e0 = __expf(leaky(a.x + dd.x));
    float e1 = __expf(leaky(a.y + dd.y));
    p0 += e0; p1 += e1;
    float q = hh ? e1 : e0;
    uint4 v = *(const uint4*)(Hb + (size_t)s * 128 + cbase);
    acc0 = fmaf(q, blo(v.x), acc0); acc1 = fmaf(q, bhi(v.x), acc1);
    acc2 = fmaf(q, blo(v.y), acc2); acc3 = fmaf(q, bhi(v.y), acc3);
    acc4 = fmaf(q, blo(v.z), acc4); acc5 = fmaf(q, bhi(v.z), acc5);
    acc6 = fmaf(q, blo(v.w), acc6); acc7 = fmaf(q, bhi(v.w), acc7);
  }
  // self-loop + normalization
  float2 ai = *(const float2*)(als + 2 * i);
  float es0 = __expf(leaky(ai.x + dd.x));
  float es1 = __expf(leaky(ai.y + dd.y));
  float rsel = hh ? (0.5f / (p1 + es1)) : (0.5f / (p0 + es0));
  float wself = hh ? es1 : es0;
  uint4 u = *(const uint4*)(Hb + (size_t)i * 128 + cbase);
  acc0 = (acc0 + wself * blo(u.x)) * rsel; acc1 = (acc1 + wself * bhi(u.x)) * rsel;
  acc2 = (acc2 + wself * blo(u.y)) * rsel; acc3 = (acc3 + wself * bhi(u.y)) * rsel;
  acc4 = (acc4 + wself * blo(u.z)) * rsel; acc5 = (acc5 + wself * bhi(u.z)) * rsel;
  acc6 = (acc6 + wself * blo(u.w)) * rsel; acc7 = (acc7 + wself * bhi(u.w)) * rsel;
  // head combine: lane p (head0 ch 8p..) + lane 8+p (head1 ch 8p..)
  acc0 += __shfl_xor(acc0, 8, 64); acc1 += __shfl_xor(acc1, 8, 64);
  acc2 += __shfl_xor(acc2, 8, 64); acc3 += __shfl_xor(acc3, 8, 64);
  acc4 += __shfl_xor(acc4, 8, 64); acc5 += __shfl_xor(acc5, 8, 64);
  acc6 += __shfl_xor(acc6, 8, 64); acc7 += __shfl_xor(acc7, 8, 64);
  float4 b0 = *(const float4*)(bias + 8 * p);
  float4 b1 = *(const float4*)(bias + 8 * p + 4);
  float v0 = acc0 + b0.x, v1 = acc1 + b0.y, v2 = acc2 + b0.z, v3 = acc3 + b0.w;
  float v4 = acc4 + b1.x, v5 = acc5 + b1.y, v6 = acc6 + b1.z, v7 = acc7 + b1.w;
  // log_softmax over 64 ch = 8 lanes x 8 vals (lanes 8-15 hold identical sums)
  float mv = fmaxf(fmaxf(fmaxf(v0, v1), fmaxf(v2, v3)),
                   fmaxf(fmaxf(v4, v5), fmaxf(v6, v7)));
#pragma unroll
  for (int mm = 4; mm > 0; mm >>= 1) mv = fmaxf(mv, __shfl_xor(mv, mm, 64));
  float sv = __expf(v0 - mv) + __expf(v1 - mv) + __expf(v2 - mv) + __expf(v3 - mv) +
             __expf(v4 - mv) + __expf(v5 - mv) + __expf(v6 - mv) + __expf(v7 - mv);
#pragma unroll
  for (int mm = 4; mm > 0; mm >>= 1) sv += __shfl_xor(sv, mm, 64);
  float ls = mv + __logf(sv);
  if (hh == 0) {
    *(float4*)(out + (size_t)i * 64 + 8 * p) =
        make_float4(v0 - ls, v1 - ls, v2 - ls, v3 - ls);
    *(float4*)(out + (size_t)i * 64 + 8 * p + 4) =
        make_float4(v4 - ls, v5 - ls, v6 - ls, v7 - ls);
  }
}

extern "C" void kernel_launch(void* const* d_in, const int* in_sizes, int n_in, void* d_out,
                              int out_size, void* d_ws, size_t ws_size, hipStream_t stream) {
  const float* x      = (const float*)d_in[0];
  const int* eidx     = (const int*)d_in[1];
  const float* W_gcn1 = (const float*)d_in[2];
  const float* b_gcn1 = (const float*)d_in[3];
  const float* bn1_g  = (const float*)d_in[4];
  const float* bn1_b  = (const float*)d_in[5];
  const float* bn1_m  = (const float*)d_in[6];
  const float* bn1_v  = (const float*)d_in[7];
  const float* W_gat1 = (const float*)d_in[8];
  const float* a_src1 = (const float*)d_in[9];
  const float* a_dst1 = (const float*)d_in[10];
  const float* b_gat1 = (const float*)d_in[11];
  const float* W_gcn2 = (const float*)d_in[12];
  const float* b_gcn2 = (const float*)d_in[13];
  const float* bn2_g  = (const float*)d_in[14];
  const float* bn2_b  = (const float*)d_in[15];
  const float* bn2_m  = (const float*)d_in[16];
  const float* bn2_v  = (const float*)d_in[17];
  const float* W_gat2 = (const float*)d_in[18];
  const float* a_src2 = (const float*)d_in[19];
  const float* a_dst2 = (const float*)d_in[20];
  const float* b_gat2 = (const float*)d_in[21];

  char* ws = (char*)d_ws;
  size_t o = 0;
  auto take = [&](size_t bytes) {
    char* p = ws + o;
    o = (o + bytes + 255) & ~(size_t)255;
    return p;
  };
  int* srcs    = (int*)take((size_t)N_EDGES * 4);
  int* dstsb   = (int*)take((size_t)N_EDGES * 4);
  int* deg     = (int*)take((size_t)(N_NODES + 64) * 4);  // +1 int (gbase), memset together
  int* gbase   = deg + N_NODES;
  int* roff    = (int*)take((size_t)N_NODES * 4);
  int* cursor  = (int*)take((size_t)N_NODES * 4);
  int* adj     = (int*)take((size_t)N_EDGES * 4);
  float* en    = (float*)take((size_t)N_EDGES * 4);
  float* dinv  = (float*)take((size_t)N_NODES * 4);
  float* als   = (float*)take((size_t)2 * N_NODES * 4);
  float* ald   = (float*)take((size_t)2 * N_NODES * 4);
  float* sc1   = (float*)take(128 * 4);
  float* sh1   = (float*)take(128 * 4);
  float* sc2   = (float*)take(128 * 4);
  float* sh2   = (float*)take(128 * 4);
  unsigned short* Wt1  = (unsigned short*)take((size_t)128 * 128 * 2);
  unsigned short* WtG1 = (unsigned short*)take((size_t)256 * 128 * 2);
  unsigned short* Wt2  = (unsigned short*)take((size_t)128 * 128 * 2);
  unsigned short* WtG2 = (unsigned short*)take((size_t)128 * 128 * 2);
  unsigned short* Hb   = (unsigned short*)take((size_t)N_NODES * 256 * 2);
  unsigned short* Pb   = (unsigned short*)take((size_t)N_NODES * 128 * 2);
  (void)ws_size; (void)in_sizes; (void)n_in; (void)out_size;

  int eb = (N_EDGES + 255) / 256;
  int nb = (N_NODES + 255) / 256;
  int wb = (N_NODES + 3) / 4;              // wave per node (gat_pull128)
  int qb = ((N_NODES + 3) / 4 + 3) / 4;    // wave per 4 nodes (gcn_pull, lsm)
  int gb = (N_NODES + 63) / 64;            // MFMA-GEMM blocks

  // CSR build + prep
  hipMemsetAsync(deg, 0, (size_t)(N_NODES + 1) * 4, stream);
  k_convert<<<eb, 256, 0, stream>>>(eidx, srcs, dstsb, deg, W_gcn1, W_gat1, W_gcn2, W_gat2,
                                    Wt1, WtG1, Wt2, WtG2, b_gcn1, bn1_g, bn1_b, bn1_m, bn1_v,
                                    b_gcn2, bn2_g, bn2_b, bn2_m, bn2_v, sc1, sh1, sc2, sh2);
  k_offsets<<<nb, 256, 0, stream>>>(deg, gbase, roff, cursor, dinv);
  k_fill<<<eb, 256, 0, stream>>>(srcs, dstsb, cursor, adj, dinv, en);

  // Layer pipeline (all intermediates bf16; gat_al fused into GEMM epilogues;
  // edge-exp stage fused into the GAT pulls)
  gemm_mfma<128, 0><<<gb, 256, 0, stream>>>(x, Wt1, Hb, (const float*)nullptr,
                                            (const float*)nullptr, 0, nullptr, nullptr,
                                            nullptr, nullptr);
  gcn_pull<<<qb, 256, 0, stream>>>(Hb, adj, roff, deg, en, dinv, Pb);
  gemm_mfma<256, 1><<<gb, 256, 0, stream>>>(Pb, WtG1, Hb, sc1, sh1, 2, a_src1, a_dst1,
                                            als, ald);
  gat_pull128<<<wb, 256, 0, stream>>>(Hb, adj, roff, deg, als, ald, b_gat1, Pb);
  gemm_mfma<128, 0><<<gb, 256, 0, stream>>>(Pb, Wt2, Hb, (const float*)nullptr,
                                            (const float*)nullptr, 1, nullptr, nullptr,
                                            nullptr, nullptr);
  gcn_pull<<<qb, 256, 0, stream>>>(Hb, adj, roff, deg, en, dinv, Pb);
  gemm_mfma<128, 1><<<gb, 256, 0, stream>>>(Pb, WtG2, Hb, sc2, sh2, 2, a_src2, a_dst2,
                                            als, ald);
  gat_pull64_lsm<<<qb, 256, 0, stream>>>(Hb, adj, roff, deg, als, ald, b_gat2,
                                         (float*)d_out);
}